// Round 11
// baseline (676.253 us; speedup 1.0000x reference)
//
#include <hip/hip_runtime.h>
#include <hip/hip_fp16.h>

static constexpr int B  = 4;
static constexpr int H0 = 256, W0 = 448, HW0 = H0 * W0;   // full
static constexpr int H1 = 128, W1 = 224, HW1 = H1 * W1;   // half
static constexpr int H2 = 64,  W2 = 112, HW2 = H2 * W2;   // quarter

typedef _Float16 half8_t __attribute__((ext_vector_type(8)));
typedef _Float16 half4_t __attribute__((ext_vector_type(4)));
typedef float floatx4 __attribute__((ext_vector_type(4)));

static constexpr int NC_F = (W0 + 1) * (H0 + 1);   // 115393
static constexpr int NC_H = (W1 + 1) * (H1 + 1);   // 29025
static constexpr int NC_Q = (W2 + 1) * (H2 + 1);   // 7345

// record strides in dwords
static constexpr int RS_F = 20;   // u0=(im0,im1) u1=(im2,sig) u2..17=feat pairs u18=dxf u19=dyf
static constexpr int RS_H = 36;   // 32 feat dwords + dxf,dyf + pad
static constexpr int RS_Q = 52;   // 48 feat dwords + dxf,dyf + pad

// cnt region layout (contiguous, zeroed once): F(2B*NC_F), H(2B*NC_H), Q(2B*NC_Q)
static constexpr int SZ_F = 2 * B * NC_F;   // 923144
static constexpr int SZ_H = 2 * B * NC_H;   // 232200
static constexpr int SZ_Q = 2 * B * NC_Q;   // 58760
static constexpr int CNT_TOTAL = SZ_F + SZ_H + SZ_Q;

// hierarchical scan chunking (atomic-free)
static constexpr int CHUNK = 16384;                       // cells per block
static constexpr int NCH_F = (SZ_F + CHUNK - 1) / CHUNK;  // 57
static constexpr int NCH_H = (SZ_H + CHUNK - 1) / CHUNK;  // 15
static constexpr int NCH_Q = (SZ_Q + CHUNK - 1) / CHUNK;  // 4
static constexpr int NCHUNKS = NCH_F + NCH_H + NCH_Q;     // 76

// ---------------- workspace layout (floats) ----------------
static constexpr size_t OFF_MEAN   = 0;                              // 256
static constexpr size_t OFF_CNT    = 256;                            // CNT_TOTAL
static constexpr size_t ZERO_FLOATS = OFF_CNT + CNT_TOTAL;
static constexpr size_t OFF_IMGC   = ZERO_FLOATS;                    // 8*3*HW0 planar f32
static constexpr size_t OFF_BUFA   = OFF_IMGC + (size_t)8 * 3 * HW0; // 8-batch NHWC f16 ping
static constexpr size_t OFF_BUFB   = OFF_BUFA + (size_t)4 * 32 * HW0;
static constexpr size_t OFF_FLOW   = OFF_BUFB + (size_t)4 * 32 * HW0;  // 2 dirs * B*2*HW0
static constexpr size_t OFF_FLH    = OFF_FLOW + (size_t)2 * B * 2 * HW0;
static constexpr size_t OFF_FLQ    = OFF_FLH + (size_t)2 * B * 2 * HW1;
static constexpr size_t OFF_WT2 = OFF_FLQ + (size_t)2 * B * 2 * HW2;
static constexpr size_t OFF_WT3 = OFF_WT2 + 4608;
static constexpr size_t OFF_WT4 = OFF_WT3 + 9216;
static constexpr size_t OFF_WT5 = OFF_WT4 + 18432;
static constexpr size_t OFF_WT6 = OFF_WT5 + 27648;
static constexpr size_t OFF_CS   = OFF_WT6 + 41472;                  // uint2 per cell = 2*CNT_TOTAL
static constexpr size_t OFF_CURS = OFF_CS + (size_t)2 * CNT_TOTAL;   // CNT_TOTAL
static constexpr size_t OFF_TPRE = OFF_CURS + CNT_TOTAL;             // NCHUNKS*256
static constexpr size_t OFF_PSUM = OFF_TPRE + (size_t)NCHUNKS * 256; // 128
static constexpr size_t OFF_RECS = OFF_PSUM + 128;                   // 2B*HW0*RS_F (max)
static constexpr size_t WS_FLOATS = OFF_RECS + (size_t)2 * B * HW0 * RS_F;

// ---------------- output layout (floats) ----------------
static constexpr size_t O_IMG = 0;
static constexpr size_t O_F1  = O_IMG + (size_t)B * 6 * HW0;
static constexpr size_t O_F2  = O_F1  + (size_t)B * 64 * HW0;
static constexpr size_t O_F3  = O_F2  + (size_t)B * 128 * HW1;
static constexpr size_t O_SIG = O_F3  + (size_t)B * 192 * HW2;

__device__ inline void h2f(unsigned u, float& lo, float& hi) {
  __half2 h = *reinterpret_cast<__half2*>(&u);
  float2 f = __half22float2(h);
  lo = f.x; hi = f.y;
}
__device__ inline unsigned f2h(float lo, float hi) {
  __half2 h = __floats2half2_rn(lo, hi);
  return *reinterpret_cast<unsigned*>(&h);
}

// chunk id -> (region offset, region size, chunk-in-region)
__device__ inline void chunk_map(int b, int& off, int& sz, int& ci) {
  if (b < NCH_F)              { off = 0;           sz = SZ_F; ci = b; }
  else if (b < NCH_F + NCH_H) { off = SZ_F;        sz = SZ_H; ci = b - NCH_F; }
  else                        { off = SZ_F + SZ_H; sz = SZ_Q; ci = b - NCH_F - NCH_H; }
}

// ---------------- mean over (img0,img1) per batch ----------------
__global__ __launch_bounds__(256) void k_mean(const float* __restrict__ img0,
                                              const float* __restrict__ img1,
                                              float* __restrict__ msum, int perImg) {
  int b = blockIdx.y;
  float s = 0.f;
  int tot = 2 * perImg;
  for (int i = blockIdx.x * blockDim.x + threadIdx.x; i < tot; i += gridDim.x * blockDim.x) {
    s += (i < perImg) ? img0[(size_t)b * perImg + i] : img1[(size_t)b * perImg + (i - perImg)];
  }
#pragma unroll
  for (int o = 32; o > 0; o >>= 1) s += __shfl_down(s, o);
  __shared__ float red[4];
  int lane = threadIdx.x & 63, wid = threadIdx.x >> 6;
  if (lane == 0) red[wid] = s;
  __syncthreads();
  if (threadIdx.x == 0) atomicAdd(&msum[b], red[0] + red[1] + red[2] + red[3]);
}

__global__ __launch_bounds__(256) void k_submean(const float* __restrict__ img0,
                                                 const float* __restrict__ img1,
                                                 const float* __restrict__ msum,
                                                 float* __restrict__ imgc, float invCnt) {
  const int perImg = 3 * HW0;
  int i = blockIdx.x * 256 + threadIdx.x;
  if (i >= 8 * perImg) return;
  int n = i / perImg;
  int r = i - n * perImg;
  int b = n & 3;
  float m = msum[b] * invCnt;
  float v = (n < 4) ? img0[(size_t)b * perImg + r] : img1[(size_t)b * perImg + r];
  imgc[i] = v - m;
}

// ---------------- cal_inter_flow (t=0.5, closed form, no trig) + fused count ----------------
__global__ __launch_bounds__(256) void k_interflow2(
    const float* __restrict__ f01, const float* __restrict__ s01,
    const float* __restrict__ f10, const float* __restrict__ s10,
    float* __restrict__ outBase, unsigned* __restrict__ cntF) {
  constexpr int NCX = W0 + 1;
  int i = blockIdx.x * 256 + threadIdx.x;
  if (i >= 2 * B * HW0) return;
  int nb = i / HW0;            // dir*B + b
  int px = i - nb * HW0;
  int dir = nb >> 2, b = nb & 3;
  const float* flo = dir ? f10 : f01;
  const float* sigma = dir ? s10 : s01;
  float fx = flo[((size_t)(b * 2 + 0)) * HW0 + px];
  float fy = flo[((size_t)(b * 2 + 1)) * HW0 + px];
  float sg = sigma[(size_t)b * HW0 + px];
  float ftx, fty;
  if (fabsf(sg) < 0.01f) {
    ftx = 0.5f * fx; fty = 0.5f * fy;
  } else {
    float g = (1.f - sqrtf(fmaxf(0.f, 1.f - sg * sg))) / (2.f * sg);
    ftx = 0.5f * fx - g * fy;
    fty = 0.5f * fy + g * fx;
  }
  outBase[((size_t)(nb * 2 + 0)) * HW0 + px] = ftx;
  outBase[((size_t)(nb * 2 + 1)) * HW0 + px] = fty;
  int sw = px % W0, sh = px / W0;
  float tx = (float)sw + ftx, ty = (float)sh + fty;
  int x0 = (int)floorf(tx), y0 = (int)floorf(ty);
  if (x0 >= -1 && x0 <= W0 - 1 && y0 >= -1 && y0 <= H0 - 1)
    atomicAdd(&cntF[nb * NC_F + (y0 + 1) * NCX + (x0 + 1)], 1u);
}

// ---------------- antialiased downsample of flow + fused count ----------------
template <int F, int Hd, int Wd>
__global__ __launch_bounds__(256) void k_downflow2(
    const float* __restrict__ in, float* __restrict__ out,
    unsigned* __restrict__ cnt) {
  constexpr int HWd = Hd * Wd;
  constexpr int NCX = Wd + 1;
  constexpr int NC  = (Wd + 1) * (Hd + 1);
  int i = blockIdx.x * 256 + threadIdx.x;
  if (i >= 2 * B * HWd) return;
  int nb = i / HWd;
  int px = i - nb * HWd;
  int ow = px % Wd, oh = px / Wd;
  float cy = (oh + 0.5f) * F - 0.5f;
  float cx = (ow + 0.5f) * F - 0.5f;
  int ylo = (int)floorf(cy) - F + 1;
  int xlo = (int)floorf(cx) - F + 1;
  const float* ipx = in + ((size_t)(nb * 2 + 0)) * HW0;
  const float* ipy = in + ((size_t)(nb * 2 + 1)) * HW0;
  float ax = 0.f, ay = 0.f, wn = 0.f;
  for (int jy = 0; jy < 2 * F; jy++) {
    int y = ylo + jy;
    if ((unsigned)y >= (unsigned)H0) continue;
    float wy = 1.f - fabsf((float)y - cy) / (float)F;
    for (int jx = 0; jx < 2 * F; jx++) {
      int x = xlo + jx;
      if ((unsigned)x >= (unsigned)W0) continue;
      float wx = 1.f - fabsf((float)x - cx) / (float)F;
      float ww = wy * wx;
      ax += ww * ipx[(size_t)y * W0 + x];
      ay += ww * ipy[(size_t)y * W0 + x];
      wn += ww;
    }
  }
  float s = 1.f / (wn * (float)F);
  float fx = ax * s, fy = ay * s;
  out[((size_t)(nb * 2 + 0)) * HWd + px] = fx;
  out[((size_t)(nb * 2 + 1)) * HWd + px] = fy;
  float tx = (float)ow + fx, ty = (float)oh + fy;
  int x0 = (int)floorf(tx), y0 = (int)floorf(ty);
  if (x0 >= -1 && x0 <= Wd - 1 && y0 >= -1 && y0 <= Hd - 1)
    atomicAdd(&cnt[nb * NC + (y0 + 1) * NCX + (x0 + 1)], 1u);
}

// ---------------- all weight transforms fused ----------------
__global__ __launch_bounds__(256) void k_wtrans_all(
    const float* __restrict__ w2, const float* __restrict__ w3,
    const float* __restrict__ w4, const float* __restrict__ w5,
    const float* __restrict__ w6,
    _Float16* __restrict__ o2, _Float16* __restrict__ o3,
    _Float16* __restrict__ o4, _Float16* __restrict__ o5,
    _Float16* __restrict__ o6) {
  int i = blockIdx.x * 256 + threadIdx.x;
  const float* w; _Float16* o; int COUT, CIN, base;
  if      (i <   9216) { w = w2; o = o2; COUT = 32; CIN = 32; base = 0; }
  else if (i <  27648) { w = w3; o = o3; COUT = 64; CIN = 32; base = 9216; }
  else if (i <  64512) { w = w4; o = o4; COUT = 64; CIN = 64; base = 27648; }
  else if (i < 119808) { w = w5; o = o5; COUT = 96; CIN = 64; base = 64512; }
  else if (i < 202752) { w = w6; o = o6; COUT = 96; CIN = 96; base = 119808; }
  else return;
  int j = i - base;
  int q = j % 9;
  int rest = j / 9;
  int ci = rest % CIN;
  int co = rest / CIN;
  o[((size_t)q * COUT + co) * CIN + ci] = (_Float16)w[j];
}

// ---------------- fused conv1(3->32 VALU, LDS) + conv2(32->32 MFMA) ----------------
// block: 16x16 output px, all 32 co. LDS: conv1 tile 18x18x32 f16 [chunk][px][8].
__global__ __launch_bounds__(256) void conv12_fused(
    const float* __restrict__ imgc,
    const float* __restrict__ w1, const float* __restrict__ b1, const float* __restrict__ a1,
    const _Float16* __restrict__ wT2, const float* __restrict__ b2, const float* __restrict__ a2,
    _Float16* __restrict__ outp) {
  __shared__ _Float16 tile[4 * 324 * 8];
  __shared__ float wsm[32 * 27];
  __shared__ float bsm[32];
  int gx = gridDim.x, gz = gridDim.z;
  int T = gx * gz;
  int lb = (int)blockIdx.z * gx + blockIdx.x;
  lb = (lb & 7) * (T >> 3) + (lb >> 3);        // XCD chunking
  int n = lb % gz;
  int tile_id = lb / gz;
  int tx = tile_id % 28, ty = tile_id / 28;
  int ow0 = tx * 16, oh0t = ty * 16;
  int tid = threadIdx.x;
  for (int i = tid; i < 32 * 27; i += 256) wsm[i] = w1[i];
  if (tid < 32) bsm[tid] = b1[tid];
  __syncthreads();
  float a1v = a1[0];
  // phase 1: conv1 into LDS for 18x18 halo tile
  for (int p = tid; p < 324; p += 256) {
    int ly = p / 18, lx = p % 18;
    int y = oh0t - 1 + ly, x = ow0 - 1 + lx;
    if ((unsigned)y >= (unsigned)H0 || (unsigned)x >= (unsigned)W0) {
      half8_t z = {};
#pragma unroll
      for (int g = 0; g < 4; g++) *(half8_t*)&tile[((size_t)g * 324 + p) * 8] = z;
      continue;
    }
    float xv[27];
#pragma unroll
    for (int ci = 0; ci < 3; ci++) {
      const float* iq = imgc + ((size_t)(n * 3 + ci)) * HW0;
#pragma unroll
      for (int ky = 0; ky < 3; ky++) {
        int yy = y - 1 + ky;
        bool yv = (unsigned)yy < (unsigned)H0;
        const float* row = iq + (size_t)yy * W0;
#pragma unroll
        for (int kx = 0; kx < 3; kx++) {
          int xx = x - 1 + kx;
          xv[ci * 9 + ky * 3 + kx] = (yv && (unsigned)xx < (unsigned)W0) ? row[xx] : 0.f;
        }
      }
    }
#pragma clang loop unroll(disable)
    for (int pass = 0; pass < 2; pass++) {
      float acc[16];
#pragma unroll
      for (int k = 0; k < 16; k++) acc[k] = bsm[pass * 16 + k];
#pragma unroll
      for (int k = 0; k < 16; k++) {
        const float* wp = &wsm[(pass * 16 + k) * 27];
#pragma unroll
        for (int j = 0; j < 27; j++) acc[k] += xv[j] * wp[j];
      }
#pragma unroll
      for (int g = 0; g < 2; g++) {
        half8_t h;
#pragma unroll
        for (int k = 0; k < 8; k++) {
          float v = acc[g * 8 + k];
          v = v > 0.f ? v : a1v * v;
          h[k] = (_Float16)v;
        }
        *(half8_t*)&tile[((size_t)(pass * 2 + g) * 324 + p) * 8] = h;
      }
    }
  }
  __syncthreads();
  // phase 2: conv2 MFMA from LDS (CIN=32, COUT=32, stride 1, TROWS=4/wave)
  int lane = tid & 63, wave = tid >> 6;
  int l15 = lane & 15, lhi = lane >> 4;
  floatx4 acc2[2][4] = {};
  const _Float16* wA = wT2 + (size_t)l15 * 32;
  const _Float16* wB = wT2 + (size_t)(16 + l15) * 32;
  int ci = lhi * 8;
#pragma unroll
  for (int dxi = 0; dxi < 3; dxi++) {
    int lx = l15 + dxi;
    half8_t a0[3], a1f[3];
#pragma unroll
    for (int dy = 0; dy < 3; dy++) {
      int q = dy * 3 + dxi;
      a0[dy]  = *(const half8_t*)(wA + (size_t)q * 32 * 32 + ci);
      a1f[dy] = *(const half8_t*)(wB + (size_t)q * 32 * 32 + ci);
    }
#pragma unroll
    for (int y6 = 0; y6 < 6; y6++) {
      int ly = wave * 4 + y6;
      half8_t bf = *(const half8_t*)&tile[((size_t)lhi * 324 + ly * 18 + lx) * 8];
#pragma unroll
      for (int dy = 0; dy < 3; dy++) {
        int t = y6 - dy;
        if (t < 0 || t >= 4) continue;
        acc2[0][t] = __builtin_amdgcn_mfma_f32_16x16x32_f16(a0[dy], bf, acc2[0][t], 0, 0, 0);
        acc2[1][t] = __builtin_amdgcn_mfma_f32_16x16x32_f16(a1f[dy], bf, acc2[1][t], 0, 0, 0);
      }
    }
  }
  float aP = a2[0];
#pragma unroll
  for (int h = 0; h < 2; h++) {
    float bia[4];
#pragma unroll
    for (int r = 0; r < 4; r++) bia[r] = b2[h * 16 + lhi * 4 + r];
#pragma unroll
    for (int t = 0; t < 4; t++) {
      half4_t hh;
#pragma unroll
      for (int r = 0; r < 4; r++) {
        float v = acc2[h][t][r] + bia[r];
        v = v > 0.f ? v : aP * v;
        hh[r] = (_Float16)v;
      }
      *(half4_t*)(outp + (((size_t)n * H0 + oh0t + wave * 4 + t) * W0 + ow0 + l15) * 32 +
                  h * 16 + lhi * 4) = hh;
    }
  }
}

// ---------------- MFMA conv (row-reuse; 32co x (4*TROWS)x16 px block) ----------------
template <int CIN, int COUT, int STRIDE, int TROWS>
__global__ __launch_bounds__(256) void conv_mfma(
    const _Float16* __restrict__ in, const _Float16* __restrict__ wT,
    const float* __restrict__ bias, const float* __restrict__ alpha,
    _Float16* __restrict__ outp, int Hin, int Win, int Hout, int Wout) {
  int gx = gridDim.x, gy = gridDim.y, gz = gridDim.z;
  int T = gx * gy * gz;
  int lb = ((int)blockIdx.z * gy + blockIdx.y) * gx + blockIdx.x;
  lb = (lb & 7) * (T >> 3) + (lb >> 3);
  int cob  = lb % gy;
  int n    = (lb / gy) % gz;
  int tile = lb / (gy * gz);
  int lane = threadIdx.x & 63, wave = threadIdx.x >> 6;
  int l15 = lane & 15, lhi = lane >> 4;
  int tiles_x = Wout >> 4;
  int tx = tile % tiles_x, ty = tile / tiles_x;
  int ow0 = tx << 4;
  int oh0 = ty * (4 * TROWS) + wave * TROWS;
  int co0 = cob * 32;
  floatx4 acc[2][TROWS] = {};
  const _Float16* ip = in + (size_t)n * Hin * Win * CIN;
  int x_base = (ow0 + l15) * STRIDE;
  int ybase = oh0 * STRIDE - 1;
  constexpr int NY = (TROWS - 1) * STRIDE + 3;
  const _Float16* wA = wT + (size_t)(co0 + l15) * CIN;
  const _Float16* wB = wT + (size_t)(co0 + 16 + l15) * CIN;
  for (int kc = 0; kc < CIN / 32; kc++) {
    int ci = kc * 32 + lhi * 8;
#pragma unroll
    for (int dxi = 0; dxi < 3; dxi++) {
      int x = x_base + dxi - 1;
      bool xv = (unsigned)x < (unsigned)Win;
      int xc = x < 0 ? 0 : (x >= Win ? Win - 1 : x);
      half8_t a0[3], a1[3];
#pragma unroll
      for (int dy = 0; dy < 3; dy++) {
        int q = dy * 3 + dxi;
        a0[dy] = *(const half8_t*)(wA + (size_t)q * COUT * CIN + ci);
        a1[dy] = *(const half8_t*)(wB + (size_t)q * COUT * CIN + ci);
      }
#pragma unroll
      for (int y6 = 0; y6 < NY; y6++) {
        int y = ybase + y6;
        if ((unsigned)y >= (unsigned)Hin) continue;   // wave-uniform; skip == zero-pad
        half8_t bf = *(const half8_t*)(ip + ((size_t)y * Win + xc) * CIN + ci);
        half8_t z = {};
        bf = xv ? bf : z;
#pragma unroll
        for (int dy = 0; dy < 3; dy++) {
          int tnum = y6 - dy;
          if (tnum < 0 || tnum % STRIDE != 0) continue;
          int t = tnum / STRIDE;
          if (t >= TROWS) continue;
          acc[0][t] = __builtin_amdgcn_mfma_f32_16x16x32_f16(a0[dy], bf, acc[0][t], 0, 0, 0);
          acc[1][t] = __builtin_amdgcn_mfma_f32_16x16x32_f16(a1[dy], bf, acc[1][t], 0, 0, 0);
        }
      }
    }
  }
  float aP = alpha[0];
#pragma unroll
  for (int h = 0; h < 2; h++) {
    float bia[4];
#pragma unroll
    for (int r = 0; r < 4; r++) bia[r] = bias[co0 + h * 16 + lhi * 4 + r];
#pragma unroll
    for (int t = 0; t < TROWS; t++) {
      half4_t hh;
#pragma unroll
      for (int r = 0; r < 4; r++) {
        float v = acc[h][t][r] + bia[r];
        v = v > 0.f ? v : aP * v;
        hh[r] = (_Float16)v;
      }
      *(half4_t*)(outp + (((size_t)n * Hout + oh0 + t) * Wout + ow0 + l15) * COUT +
                  co0 + h * 16 + lhi * 4) = hh;
    }
  }
}

// ---------------- hierarchical scan (atomic-free): part -> apply ----------------
__global__ __launch_bounds__(256) void k_scan_part(
    const unsigned* __restrict__ cnt, unsigned* __restrict__ tpre,
    unsigned* __restrict__ psum) {
  int b = blockIdx.x, t = threadIdx.x;
  int off, sz, ci;
  chunk_map(b, off, sz, ci);
  int base = off + ci * CHUNK + t * 64;
  int lim = off + min(sz, (ci + 1) * CHUNK);
  unsigned s = 0;
  for (int j = 0; j < 64; j++) {
    int idx = base + j;
    if (idx < lim) s += cnt[idx];
  }
  __shared__ unsigned sm[256];
  sm[t] = s;
  __syncthreads();
  for (int o = 1; o < 256; o <<= 1) {
    unsigned v = (t >= o) ? sm[t - o] : 0u;
    __syncthreads();
    sm[t] += v;
    __syncthreads();
  }
  unsigned incl = sm[t];
  tpre[b * 256 + t] = incl - s;        // exclusive
  if (t == 255) psum[b] = incl;
}

__global__ __launch_bounds__(256) void k_scan_apply(
    const unsigned* __restrict__ cnt, const unsigned* __restrict__ tpre,
    const unsigned* __restrict__ psum,
    uint2* __restrict__ cs, unsigned* __restrict__ curs) {
  int b = blockIdx.x, t = threadIdx.x;
  int off, sz, ci;
  chunk_map(b, off, sz, ci);
  __shared__ unsigned cbs;
  if (t == 0) {
    int first = (off == 0) ? 0 : (off == SZ_F ? NCH_F : NCH_F + NCH_H);
    unsigned c = 0;
    for (int k = first; k < first + ci; k++) c += psum[k];
    cbs = c;
  }
  __syncthreads();
  int base = off + ci * CHUNK + t * 64;
  int lim = off + min(sz, (ci + 1) * CHUNK);
  unsigned run = cbs + tpre[b * 256 + t];
  for (int j = 0; j < 64; j++) {
    int idx = base + j;
    if (idx < lim) {
      unsigned c = cnt[idx];
      cs[idx] = make_uint2(run, c);
      curs[idx] = run;
      run += c;
    }
  }
}

// ---------------- pack-at-slot: full res (both dirs) ----------------
__global__ __launch_bounds__(256) void k_pack_full(
    const float* __restrict__ imgc, const _Float16* __restrict__ featN,
    const float* __restrict__ s01, const float* __restrict__ s10,
    const float* __restrict__ flowB,
    float* __restrict__ recs, unsigned* __restrict__ curs) {
  constexpr int NCX = W0 + 1;
  int px = blockIdx.x * 256 + threadIdx.x;
  int b = blockIdx.y;
  int dir = blockIdx.z;
  if (px >= HW0) return;
  int nb = dir * B + b;
  float fx = flowB[((size_t)(nb * 2 + 0)) * HW0 + px];
  float fy = flowB[((size_t)(nb * 2 + 1)) * HW0 + px];
  int sw = px % W0, sh = px / W0;
  float tx = (float)sw + fx, ty = (float)sh + fy;
  float x0f = floorf(tx), y0f = floorf(ty);
  int x0 = (int)x0f, y0 = (int)y0f;
  if (x0 < -1 || x0 > W0 - 1 || y0 < -1 || y0 > H0 - 1) return;
  const float* imp = imgc + ((size_t)(nb * 3)) * HW0;
  float im0 = imp[px], im1 = imp[(size_t)HW0 + px], im2 = imp[(size_t)2 * HW0 + px];
  const float* sig = dir ? s10 : s01;
  float sg = sig[(size_t)b * HW0 + px];
  union { floatx4 f4[RS_F / 4]; unsigned u[RS_F]; } r;
  r.u[0] = f2h(im0, im1);
  r.u[1] = f2h(im2, sg);
  const floatx4* fp = (const floatx4*)(featN + ((size_t)nb * HW0 + px) * 32);
  union { floatx4 f; unsigned u[4]; } t;
#pragma unroll
  for (int j = 0; j < 4; j++) {
    t.f = fp[j];
    r.u[2 + 4 * j + 0] = t.u[0]; r.u[2 + 4 * j + 1] = t.u[1];
    r.u[2 + 4 * j + 2] = t.u[2]; r.u[2 + 4 * j + 3] = t.u[3];
  }
  r.u[18] = __float_as_uint(tx - x0f);
  r.u[19] = __float_as_uint(ty - y0f);
  unsigned slot = atomicAdd(&curs[nb * NC_F + (y0 + 1) * NCX + (x0 + 1)], 1u);
  floatx4* o = (floatx4*)(recs + (size_t)slot * RS_F);
#pragma unroll
  for (int j = 0; j < RS_F / 4; j++) o[j] = r.f4[j];
}

// ---------------- pack-at-slot: reduced res (both dirs) ----------------
template <int C, int Hd, int Wd, int RS>
__global__ __launch_bounds__(256) void k_pack_feat(
    const _Float16* __restrict__ featN, const float* __restrict__ flowB,
    float* __restrict__ recs, unsigned* __restrict__ curs) {
  constexpr int HWd = Hd * Wd;
  constexpr int NCX = Wd + 1;
  constexpr int NC  = (Wd + 1) * (Hd + 1);
  int px = blockIdx.x * 256 + threadIdx.x;
  int b = blockIdx.y;
  int dir = blockIdx.z;
  if (px >= HWd) return;
  int nb = dir * B + b;
  float fx = flowB[((size_t)(nb * 2 + 0)) * HWd + px];
  float fy = flowB[((size_t)(nb * 2 + 1)) * HWd + px];
  int sw = px % Wd, sh = px / Wd;
  float tx = (float)sw + fx, ty = (float)sh + fy;
  float x0f = floorf(tx), y0f = floorf(ty);
  int x0 = (int)x0f, y0 = (int)y0f;
  if (x0 < -1 || x0 > Wd - 1 || y0 < -1 || y0 > Hd - 1) return;
  union { floatx4 f4[RS / 4]; unsigned u[RS]; } r;
  const floatx4* fp = (const floatx4*)(featN + ((size_t)nb * HWd + px) * C);
#pragma unroll
  for (int j = 0; j < C / 8; j++) r.f4[j] = fp[j];
  r.u[C / 2]     = __float_as_uint(tx - x0f);
  r.u[C / 2 + 1] = __float_as_uint(ty - y0f);
#pragma unroll
  for (int j = C / 2 + 2; j < RS; j++) r.u[j] = 0;
  unsigned slot = atomicAdd(&curs[nb * NC + (y0 + 1) * NCX + (x0 + 1)], 1u);
  floatx4* o = (floatx4*)(recs + (size_t)slot * RS);
#pragma unroll
  for (int j = 0; j < RS / 4; j++) o[j] = r.f4[j];
}

// ---------------- full-res gather (both dirs, normalization fused) ----------------
__global__ __launch_bounds__(256) void k_warp_gather_full(
    const float* __restrict__ recs, const uint2* __restrict__ cs,
    float* __restrict__ outImg, float* __restrict__ outFeat, float* __restrict__ outSig) {
  constexpr int NCX = W0 + 1;
  int gx = gridDim.x;
  int T = gx * gridDim.y * gridDim.z;
  int lb = ((int)blockIdx.z * gridDim.y + blockIdx.y) * gx + blockIdx.x;
  lb = (lb & 7) * (T >> 3) + (lb >> 3);
  int q = (lb % gx) * 256 + (int)threadIdx.x;
  int b = (lb / gx) % B;
  int dir = lb / (gx * B);
  if (q >= HW0) return;
  int nb = dir * B + b;
  int qx = q % W0, qy = q / W0;
  float acc[36];
#pragma unroll
  for (int c = 0; c < 36; c++) acc[c] = 0.f;
  float dsum = 0.f;
  for (int ky = 0; ky < 2; ky++) {
    int cy = qy - 1 + ky;
    for (int kx = 0; kx < 2; kx++) {
      int cx = qx - 1 + kx;
      uint2 sc = cs[nb * NC_F + (cy + 1) * NCX + (cx + 1)];
      unsigned s0 = sc.x, cn = sc.y;
      for (unsigned s = s0; s < s0 + cn; s++) {
        const floatx4* r4 = (const floatx4*)(recs + (size_t)s * RS_F);
        floatx4 a0 = r4[0], a1 = r4[1], a2 = r4[2], a3 = r4[3], a4 = r4[4];
        union { floatx4 f; unsigned u[4]; } t;
        float ch[36]; float dxf, dyf;
        t.f = a0; h2f(t.u[0], ch[0], ch[1]);   h2f(t.u[1], ch[2], ch[35]);
                  h2f(t.u[2], ch[3], ch[4]);   h2f(t.u[3], ch[5], ch[6]);
        t.f = a1; h2f(t.u[0], ch[7], ch[8]);   h2f(t.u[1], ch[9], ch[10]);
                  h2f(t.u[2], ch[11], ch[12]); h2f(t.u[3], ch[13], ch[14]);
        t.f = a2; h2f(t.u[0], ch[15], ch[16]); h2f(t.u[1], ch[17], ch[18]);
                  h2f(t.u[2], ch[19], ch[20]); h2f(t.u[3], ch[21], ch[22]);
        t.f = a3; h2f(t.u[0], ch[23], ch[24]); h2f(t.u[1], ch[25], ch[26]);
                  h2f(t.u[2], ch[27], ch[28]); h2f(t.u[3], ch[29], ch[30]);
        t.f = a4; h2f(t.u[0], ch[31], ch[32]); h2f(t.u[1], ch[33], ch[34]);
        dxf = __uint_as_float(t.u[2]); dyf = __uint_as_float(t.u[3]);
        float wx = kx ? (1.f - dxf) : dxf;
        float wy = ky ? (1.f - dyf) : dyf;
        float w = wx * wy;
        dsum += w;
#pragma unroll
        for (int c = 0; c < 36; c++) acc[c] += w * ch[c];
      }
    }
  }
  float inv = 1.f / fmaxf(dsum, 1e-7f);
#pragma unroll
  for (int c = 0; c < 3; c++)
    outImg[((size_t)(b * 6 + dir * 3 + c)) * HW0 + q] = acc[c] * inv;
#pragma unroll
  for (int c = 0; c < 32; c++)
    outFeat[((size_t)(b * 64 + dir * 32 + c)) * HW0 + q] = acc[3 + c] * inv;
  outSig[((size_t)(b * 2 + dir)) * HW0 + q] = acc[35] * inv;
}

// ---------------- reduced-res gather (both dirs x Z chunks, normalization fused) ----------------
template <int C, int Hd, int Wd, int RS, int Z>
__global__ __launch_bounds__(256) void k_warp_gather_feat(
    const float* __restrict__ recs, const uint2* __restrict__ cs,
    float* __restrict__ outF) {
  constexpr int HWd = Hd * Wd;
  constexpr int NCX = Wd + 1;
  constexpr int NC  = (Wd + 1) * (Hd + 1);
  int gx = gridDim.x;
  int T = gx * gridDim.y * gridDim.z;
  int lb = ((int)blockIdx.z * gridDim.y + blockIdx.y) * gx + blockIdx.x;
  lb = (lb & 7) * (T >> 3) + (lb >> 3);
  int q = (lb % gx) * 256 + (int)threadIdx.x;
  int b = (lb / gx) % B;
  int dz = lb / (gx * B);
  int z = dz % Z, dir = dz / Z;
  int c0 = z * 32;
  if (q >= HWd) return;
  int nb = dir * B + b;
  int qx = q % Wd, qy = q / Wd;
  float acc[32];
#pragma unroll
  for (int c = 0; c < 32; c++) acc[c] = 0.f;
  float dsum = 0.f;
  for (int ky = 0; ky < 2; ky++) {
    int cy = qy - 1 + ky;
    for (int kx = 0; kx < 2; kx++) {
      int cx = qx - 1 + kx;
      uint2 sc = cs[nb * NC + (cy + 1) * NCX + (cx + 1)];
      unsigned s0 = sc.x, cn = sc.y;
      for (unsigned s = s0; s < s0 + cn; s++) {
        const unsigned* rp = (const unsigned*)(recs + (size_t)s * RS);
        const floatx4* r4 = (const floatx4*)rp;
        floatx4 a0 = r4[4 * z + 0], a1 = r4[4 * z + 1], a2 = r4[4 * z + 2], a3 = r4[4 * z + 3];
        float2 hd = *(const float2*)(rp + C / 2);
        union { floatx4 f; unsigned u[4]; } t;
        float ch[32];
        t.f = a0; h2f(t.u[0], ch[0], ch[1]);  h2f(t.u[1], ch[2], ch[3]);
                  h2f(t.u[2], ch[4], ch[5]);  h2f(t.u[3], ch[6], ch[7]);
        t.f = a1; h2f(t.u[0], ch[8], ch[9]);  h2f(t.u[1], ch[10], ch[11]);
                  h2f(t.u[2], ch[12], ch[13]);h2f(t.u[3], ch[14], ch[15]);
        t.f = a2; h2f(t.u[0], ch[16], ch[17]);h2f(t.u[1], ch[18], ch[19]);
                  h2f(t.u[2], ch[20], ch[21]);h2f(t.u[3], ch[22], ch[23]);
        t.f = a3; h2f(t.u[0], ch[24], ch[25]);h2f(t.u[1], ch[26], ch[27]);
                  h2f(t.u[2], ch[28], ch[29]);h2f(t.u[3], ch[30], ch[31]);
        float dxf = hd.x, dyf = hd.y;
        float wx = kx ? (1.f - dxf) : dxf;
        float wy = ky ? (1.f - dyf) : dyf;
        float w = wx * wy;
        dsum += w;
#pragma unroll
        for (int c = 0; c < 32; c++) acc[c] += w * ch[c];
      }
    }
  }
  float inv = 1.f / fmaxf(dsum, 1e-7f);
  size_t obase = ((size_t)(b * 2 * C + dir * C + c0)) * HWd + q;
#pragma unroll
  for (int c = 0; c < 32; c++) outF[obase + (size_t)c * HWd] = acc[c] * inv;
}

extern "C" void kernel_launch(void* const* d_in, const int* in_sizes, int n_in,
                              void* d_out, int out_size, void* d_ws, size_t ws_size,
                              hipStream_t stream) {
  (void)in_sizes; (void)n_in; (void)out_size;
  if (ws_size < WS_FLOATS * sizeof(float)) return;

  const float* img0    = (const float*)d_in[0];
  const float* img1    = (const float*)d_in[1];
  const float* flow01  = (const float*)d_in[2];
  const float* sigma01 = (const float*)d_in[3];
  const float* flow10  = (const float*)d_in[4];
  const float* sigma10 = (const float*)d_in[5];
  const float* wp[6]; const float* bp[6]; const float* ap[6];
  for (int i = 0; i < 6; i++) {
    wp[i] = (const float*)(d_in[6 + 3 * i]);
    bp[i] = (const float*)(d_in[7 + 3 * i]);
    ap[i] = (const float*)(d_in[8 + 3 * i]);
  }
  float* ws  = (float*)d_ws;
  float* out = (float*)d_out;

  unsigned* cntAll  = (unsigned*)(ws + OFF_CNT);
  unsigned* cntF = cntAll;
  unsigned* cntH = cntAll + SZ_F;
  unsigned* cntQ = cntAll + SZ_F + SZ_H;
  uint2*    csAll = (uint2*)(ws + OFF_CS);
  uint2*    csF = csAll, *csH = csAll + SZ_F, *csQ = csAll + SZ_F + SZ_H;
  unsigned* cursAll  = (unsigned*)(ws + OFF_CURS);
  unsigned* cursF = cursAll, *cursH = cursAll + SZ_F, *cursQ = cursAll + SZ_F + SZ_H;
  unsigned* tpre  = (unsigned*)(ws + OFF_TPRE);
  unsigned* psum  = (unsigned*)(ws + OFF_PSUM);
  float*    recs    = ws + OFF_RECS;
  _Float16* Ah = (_Float16*)(ws + OFF_BUFA);
  _Float16* Bh = (_Float16*)(ws + OFF_BUFB);
  _Float16* wt[5] = {(_Float16*)(ws + OFF_WT2), (_Float16*)(ws + OFF_WT3),
                     (_Float16*)(ws + OFF_WT4), (_Float16*)(ws + OFF_WT5),
                     (_Float16*)(ws + OFF_WT6)};
  float* flowF = ws + OFF_FLOW;
  float* flowH = ws + OFF_FLH;
  float* flowQ = ws + OFF_FLQ;

  // single upfront zero: mean + all cnt regions (~4.9 MB)
  hipMemsetAsync(ws, 0, ZERO_FLOATS * sizeof(float), stream);

  dim3 blk(256);

  k_wtrans_all<<<dim3((202752 + 255) / 256), blk, 0, stream>>>(
      wp[1], wp[2], wp[3], wp[4], wp[5], wt[0], wt[1], wt[2], wt[3], wt[4]);

  k_mean<<<dim3(32, B), blk, 0, stream>>>(img0, img1, ws + OFF_MEAN, 3 * HW0);
  k_submean<<<dim3((8 * 3 * HW0 + 255) / 256), blk, 0, stream>>>(
      img0, img1, ws + OFF_MEAN, ws + OFF_IMGC, 1.f / (6.f * (float)HW0));

  // flows + fused counts
  k_interflow2<<<dim3((2 * B * HW0 + 255) / 256), blk, 0, stream>>>(
      flow01, sigma01, flow10, sigma10, flowF, cntF);
  k_downflow2<2, H1, W1><<<dim3((2 * B * HW1 + 255) / 256), blk, 0, stream>>>(
      flowF, flowH, cntH);
  k_downflow2<4, H2, W2><<<dim3((2 * B * HW2 + 255) / 256), blk, 0, stream>>>(
      flowF, flowQ, cntQ);

  // atomic-free hierarchical scan over all 3 regions (2 dispatches)
  k_scan_part<<<dim3(NCHUNKS), blk, 0, stream>>>(cntAll, tpre, psum);
  k_scan_apply<<<dim3(NCHUNKS), blk, 0, stream>>>(cntAll, tpre, psum, csAll, cursAll);

  // fused conv1+conv2 (8 batches) -> Bh = f01
  conv12_fused<<<dim3(28 * 16, 1, 8), blk, 0, stream>>>(
      ws + OFF_IMGC, wp[0], bp[0], ap[0], wt[0], bp[1], ap[1], Bh);

  // full-res warp (both dirs): pack-at-slot -> gather
  k_pack_full<<<dim3(HW0 / 256, B, 2), blk, 0, stream>>>(
      ws + OFF_IMGC, Bh, sigma01, sigma10, flowF, recs, cursF);
  k_warp_gather_full<<<dim3(HW0 / 256, B, 2), blk, 0, stream>>>(
      recs, csF, out + O_IMG, out + O_F1, out + O_SIG);

  // conv3 s2 -> Ah ; conv4 -> Bh = f02
  conv_mfma<32, 64, 2, 4><<<dim3(14 * 8, 2, 8), blk, 0, stream>>>(
      Bh, wt[1], bp[2], ap[2], Ah, H0, W0, H1, W1);
  conv_mfma<64, 64, 1, 8><<<dim3(14 * 4, 2, 8), blk, 0, stream>>>(
      Ah, wt[2], bp[3], ap[3], Bh, H1, W1, H1, W1);

  k_pack_feat<64, H1, W1, RS_H><<<dim3(HW1 / 256, B, 2), blk, 0, stream>>>(
      Bh, flowH, recs, cursH);
  k_warp_gather_feat<64, H1, W1, RS_H, 2><<<dim3(HW1 / 256, B, 4), blk, 0, stream>>>(
      recs, csH, out + O_F2);

  // conv5 s2 -> Ah ; conv6 -> Bh = f03
  conv_mfma<64, 96, 2, 4><<<dim3(7 * 4, 3, 8), blk, 0, stream>>>(
      Bh, wt[3], bp[4], ap[4], Ah, H1, W1, H2, W2);
  conv_mfma<96, 96, 1, 4><<<dim3(7 * 4, 3, 8), blk, 0, stream>>>(
      Ah, wt[4], bp[5], ap[5], Bh, H2, W2, H2, W2);

  k_pack_feat<96, H2, W2, RS_Q><<<dim3(HW2 / 256, B, 2), blk, 0, stream>>>(
      Bh, flowQ, recs, cursQ);
  k_warp_gather_feat<96, H2, W2, RS_Q, 3><<<dim3(HW2 / 256, B, 6), blk, 0, stream>>>(
      recs, csQ, out + O_F3);
}

// Round 12
// 643.830 us; speedup vs baseline: 1.0504x; 1.0504x over previous
//
#include <hip/hip_runtime.h>
#include <hip/hip_fp16.h>

static constexpr int B  = 4;
static constexpr int H0 = 256, W0 = 448, HW0 = H0 * W0;   // full
static constexpr int H1 = 128, W1 = 224, HW1 = H1 * W1;   // half
static constexpr int H2 = 64,  W2 = 112, HW2 = H2 * W2;   // quarter

typedef _Float16 half8_t __attribute__((ext_vector_type(8)));
typedef _Float16 half4_t __attribute__((ext_vector_type(4)));
typedef float floatx4 __attribute__((ext_vector_type(4)));

static constexpr int NC_F = (W0 + 1) * (H0 + 1);   // 115393
static constexpr int NC_H = (W1 + 1) * (H1 + 1);   // 29025
static constexpr int NC_Q = (W2 + 1) * (H2 + 1);   // 7345

// record strides in dwords
static constexpr int RS_F = 20;   // u0=(im0,im1) u1=(im2,sig) u2..17=feat pairs u18=dxf u19=dyf
static constexpr int RS_H = 36;   // 32 feat dwords + dxf,dyf + pad
static constexpr int RS_Q = 52;   // 48 feat dwords + dxf,dyf + pad

// cnt region layout (contiguous, zeroed once): F(2B*NC_F), H(2B*NC_H), Q(2B*NC_Q)
static constexpr int SZ_F = 2 * B * NC_F;   // 923144
static constexpr int SZ_H = 2 * B * NC_H;   // 232200
static constexpr int SZ_Q = 2 * B * NC_Q;   // 58760
static constexpr int CNT_TOTAL = SZ_F + SZ_H + SZ_Q;

// hierarchical scan chunking (atomic-free)
static constexpr int CHUNK = 16384;                       // cells per block
static constexpr int NCH_F = (SZ_F + CHUNK - 1) / CHUNK;  // 57
static constexpr int NCH_H = (SZ_H + CHUNK - 1) / CHUNK;  // 15
static constexpr int NCH_Q = (SZ_Q + CHUNK - 1) / CHUNK;  // 4
static constexpr int NCHUNKS = NCH_F + NCH_H + NCH_Q;     // 76

// ---------------- workspace layout (floats) ----------------
static constexpr size_t OFF_MEAN   = 0;                              // 256
static constexpr size_t OFF_CNT    = 256;                            // CNT_TOTAL
static constexpr size_t ZERO_FLOATS = OFF_CNT + CNT_TOTAL;
static constexpr size_t OFF_BUFA   = ZERO_FLOATS;                    // 8-batch NHWC f16 ping
static constexpr size_t OFF_BUFB   = OFF_BUFA + (size_t)4 * 32 * HW0;
static constexpr size_t OFF_FLOW   = OFF_BUFB + (size_t)4 * 32 * HW0;  // 2 dirs * B*2*HW0
static constexpr size_t OFF_FLH    = OFF_FLOW + (size_t)2 * B * 2 * HW0;
static constexpr size_t OFF_FLQ    = OFF_FLH + (size_t)2 * B * 2 * HW1;
static constexpr size_t OFF_WT2 = OFF_FLQ + (size_t)2 * B * 2 * HW2;
static constexpr size_t OFF_WT3 = OFF_WT2 + 4608;
static constexpr size_t OFF_WT4 = OFF_WT3 + 9216;
static constexpr size_t OFF_WT5 = OFF_WT4 + 18432;
static constexpr size_t OFF_WT6 = OFF_WT5 + 27648;
static constexpr size_t OFF_CS   = OFF_WT6 + 41472;                  // uint2 per cell = 2*CNT_TOTAL
static constexpr size_t OFF_CURS = OFF_CS + (size_t)2 * CNT_TOTAL;   // CNT_TOTAL
static constexpr size_t OFF_TPRE = OFF_CURS + CNT_TOTAL;             // NCHUNKS*256
static constexpr size_t OFF_PSUM = OFF_TPRE + (size_t)NCHUNKS * 256; // 128
static constexpr size_t OFF_RECS = OFF_PSUM + 128;                   // 2B*HW0*RS_F (max)
static constexpr size_t WS_FLOATS = OFF_RECS + (size_t)2 * B * HW0 * RS_F;

// ---------------- output layout (floats) ----------------
static constexpr size_t O_IMG = 0;
static constexpr size_t O_F1  = O_IMG + (size_t)B * 6 * HW0;
static constexpr size_t O_F2  = O_F1  + (size_t)B * 64 * HW0;
static constexpr size_t O_F3  = O_F2  + (size_t)B * 128 * HW1;
static constexpr size_t O_SIG = O_F3  + (size_t)B * 192 * HW2;

__device__ inline void h2f(unsigned u, float& lo, float& hi) {
  __half2 h = *reinterpret_cast<__half2*>(&u);
  float2 f = __half22float2(h);
  lo = f.x; hi = f.y;
}
__device__ inline unsigned f2h(float lo, float hi) {
  __half2 h = __floats2half2_rn(lo, hi);
  return *reinterpret_cast<unsigned*>(&h);
}

// chunk id -> (region offset, region size, chunk-in-region)
__device__ inline void chunk_map(int b, int& off, int& sz, int& ci) {
  if (b < NCH_F)              { off = 0;           sz = SZ_F; ci = b; }
  else if (b < NCH_F + NCH_H) { off = SZ_F;        sz = SZ_H; ci = b - NCH_F; }
  else                        { off = SZ_F + SZ_H; sz = SZ_Q; ci = b - NCH_F - NCH_H; }
}

// ---------------- mean over (img0,img1) per batch ----------------
__global__ __launch_bounds__(256) void k_mean(const float* __restrict__ img0,
                                              const float* __restrict__ img1,
                                              float* __restrict__ msum, int perImg) {
  int b = blockIdx.y;
  float s = 0.f;
  int tot = 2 * perImg;
  for (int i = blockIdx.x * blockDim.x + threadIdx.x; i < tot; i += gridDim.x * blockDim.x) {
    s += (i < perImg) ? img0[(size_t)b * perImg + i] : img1[(size_t)b * perImg + (i - perImg)];
  }
#pragma unroll
  for (int o = 32; o > 0; o >>= 1) s += __shfl_down(s, o);
  __shared__ float red[4];
  int lane = threadIdx.x & 63, wid = threadIdx.x >> 6;
  if (lane == 0) red[wid] = s;
  __syncthreads();
  if (threadIdx.x == 0) atomicAdd(&msum[b], red[0] + red[1] + red[2] + red[3]);
}

// ---------------- cal_inter_flow (t=0.5, closed form, no trig) + fused count ----------------
__global__ __launch_bounds__(256) void k_interflow2(
    const float* __restrict__ f01, const float* __restrict__ s01,
    const float* __restrict__ f10, const float* __restrict__ s10,
    float* __restrict__ outBase, unsigned* __restrict__ cntF) {
  constexpr int NCX = W0 + 1;
  int i = blockIdx.x * 256 + threadIdx.x;
  if (i >= 2 * B * HW0) return;
  int nb = i / HW0;            // dir*B + b
  int px = i - nb * HW0;
  int dir = nb >> 2, b = nb & 3;
  const float* flo = dir ? f10 : f01;
  const float* sigma = dir ? s10 : s01;
  float fx = flo[((size_t)(b * 2 + 0)) * HW0 + px];
  float fy = flo[((size_t)(b * 2 + 1)) * HW0 + px];
  float sg = sigma[(size_t)b * HW0 + px];
  float ftx, fty;
  if (fabsf(sg) < 0.01f) {
    ftx = 0.5f * fx; fty = 0.5f * fy;
  } else {
    float g = (1.f - sqrtf(fmaxf(0.f, 1.f - sg * sg))) / (2.f * sg);
    ftx = 0.5f * fx - g * fy;
    fty = 0.5f * fy + g * fx;
  }
  outBase[((size_t)(nb * 2 + 0)) * HW0 + px] = ftx;
  outBase[((size_t)(nb * 2 + 1)) * HW0 + px] = fty;
  int sw = px % W0, sh = px / W0;
  float tx = (float)sw + ftx, ty = (float)sh + fty;
  int x0 = (int)floorf(tx), y0 = (int)floorf(ty);
  if (x0 >= -1 && x0 <= W0 - 1 && y0 >= -1 && y0 <= H0 - 1)
    atomicAdd(&cntF[nb * NC_F + (y0 + 1) * NCX + (x0 + 1)], 1u);
}

// ---------------- antialiased downsample of flow + fused count ----------------
template <int F, int Hd, int Wd>
__global__ __launch_bounds__(256) void k_downflow2(
    const float* __restrict__ in, float* __restrict__ out,
    unsigned* __restrict__ cnt) {
  constexpr int HWd = Hd * Wd;
  constexpr int NCX = Wd + 1;
  constexpr int NC  = (Wd + 1) * (Hd + 1);
  int i = blockIdx.x * 256 + threadIdx.x;
  if (i >= 2 * B * HWd) return;
  int nb = i / HWd;
  int px = i - nb * HWd;
  int ow = px % Wd, oh = px / Wd;
  float cy = (oh + 0.5f) * F - 0.5f;
  float cx = (ow + 0.5f) * F - 0.5f;
  int ylo = (int)floorf(cy) - F + 1;
  int xlo = (int)floorf(cx) - F + 1;
  const float* ipx = in + ((size_t)(nb * 2 + 0)) * HW0;
  const float* ipy = in + ((size_t)(nb * 2 + 1)) * HW0;
  float ax = 0.f, ay = 0.f, wn = 0.f;
  for (int jy = 0; jy < 2 * F; jy++) {
    int y = ylo + jy;
    if ((unsigned)y >= (unsigned)H0) continue;
    float wy = 1.f - fabsf((float)y - cy) / (float)F;
    for (int jx = 0; jx < 2 * F; jx++) {
      int x = xlo + jx;
      if ((unsigned)x >= (unsigned)W0) continue;
      float wx = 1.f - fabsf((float)x - cx) / (float)F;
      float ww = wy * wx;
      ax += ww * ipx[(size_t)y * W0 + x];
      ay += ww * ipy[(size_t)y * W0 + x];
      wn += ww;
    }
  }
  float s = 1.f / (wn * (float)F);
  float fx = ax * s, fy = ay * s;
  out[((size_t)(nb * 2 + 0)) * HWd + px] = fx;
  out[((size_t)(nb * 2 + 1)) * HWd + px] = fy;
  float tx = (float)ow + fx, ty = (float)oh + fy;
  int x0 = (int)floorf(tx), y0 = (int)floorf(ty);
  if (x0 >= -1 && x0 <= Wd - 1 && y0 >= -1 && y0 <= Hd - 1)
    atomicAdd(&cnt[nb * NC + (y0 + 1) * NCX + (x0 + 1)], 1u);
}

// ---------------- all weight transforms fused ----------------
__global__ __launch_bounds__(256) void k_wtrans_all(
    const float* __restrict__ w2, const float* __restrict__ w3,
    const float* __restrict__ w4, const float* __restrict__ w5,
    const float* __restrict__ w6,
    _Float16* __restrict__ o2, _Float16* __restrict__ o3,
    _Float16* __restrict__ o4, _Float16* __restrict__ o5,
    _Float16* __restrict__ o6) {
  int i = blockIdx.x * 256 + threadIdx.x;
  const float* w; _Float16* o; int COUT, CIN, base;
  if      (i <   9216) { w = w2; o = o2; COUT = 32; CIN = 32; base = 0; }
  else if (i <  27648) { w = w3; o = o3; COUT = 64; CIN = 32; base = 9216; }
  else if (i <  64512) { w = w4; o = o4; COUT = 64; CIN = 64; base = 27648; }
  else if (i < 119808) { w = w5; o = o5; COUT = 96; CIN = 64; base = 64512; }
  else if (i < 202752) { w = w6; o = o6; COUT = 96; CIN = 96; base = 119808; }
  else return;
  int j = i - base;
  int q = j % 9;
  int rest = j / 9;
  int ci = rest % CIN;
  int co = rest / CIN;
  o[((size_t)q * COUT + co) * CIN + ci] = (_Float16)w[j];
}

// ---------------- conv1 v2: 3->32, all 32 co, sequential 8-co groups, inline mean-sub ----------------
__global__ __launch_bounds__(256) void conv1_nhwc(
    const float* __restrict__ img0, const float* __restrict__ img1,
    const float* __restrict__ msum, float invCnt,
    const float* __restrict__ wgt, const float* __restrict__ bias,
    const float* __restrict__ alpha, _Float16* __restrict__ outp) {
  __shared__ float wsm[32 * 27];
  __shared__ float bsm[32];
  int n = blockIdx.z;                      // dir*4+b
  for (int i = threadIdx.x; i < 32 * 27; i += 256) wsm[i] = wgt[i];
  if (threadIdx.x < 32) bsm[threadIdx.x] = bias[threadIdx.x];
  __syncthreads();
  int b = n & 3;
  const float* ip = (n < 4 ? img0 : img1) + (size_t)b * 3 * HW0;
  float m = msum[b] * invCnt;
  int tx = blockIdx.x % 7, ty = blockIdx.x / 7;
  int ow = tx * 64 + (threadIdx.x & 63);
  int oh = ty * 4 + (threadIdx.x >> 6);
  float xv[27];
#pragma unroll
  for (int ci = 0; ci < 3; ci++) {
    const float* iq = ip + (size_t)ci * HW0;
#pragma unroll
    for (int ky = 0; ky < 3; ky++) {
      int y = oh - 1 + ky;
      bool yv = (unsigned)y < (unsigned)H0;
      const float* row = iq + (size_t)y * W0;
#pragma unroll
      for (int kx = 0; kx < 3; kx++) {
        int x = ow - 1 + kx;
        xv[ci * 9 + ky * 3 + kx] = (yv && (unsigned)x < (unsigned)W0) ? row[x] - m : 0.f;
      }
    }
  }
  float a = alpha[0];
  _Float16* ob = outp + ((size_t)(n * H0 + oh) * W0 + ow) * 32;
#pragma clang loop unroll(disable)
  for (int g = 0; g < 4; g++) {
    float acc[8];
#pragma unroll
    for (int k = 0; k < 8; k++) acc[k] = bsm[g * 8 + k];
#pragma unroll
    for (int k = 0; k < 8; k++) {
      const float* wp = &wsm[(g * 8 + k) * 27];
#pragma unroll
      for (int j = 0; j < 27; j++) acc[k] += xv[j] * wp[j];
    }
    half8_t h;
#pragma unroll
    for (int k = 0; k < 8; k++) {
      float v = acc[k];
      v = v > 0.f ? v : a * v;
      h[k] = (_Float16)v;
    }
    *(half8_t*)(ob + g * 8) = h;
  }
}

// ---------------- MFMA conv (row-reuse; 32co x (4*TROWS)x16 px block) ----------------
template <int CIN, int COUT, int STRIDE, int TROWS>
__global__ __launch_bounds__(256) void conv_mfma(
    const _Float16* __restrict__ in, const _Float16* __restrict__ wT,
    const float* __restrict__ bias, const float* __restrict__ alpha,
    _Float16* __restrict__ outp, int Hin, int Win, int Hout, int Wout) {
  int gx = gridDim.x, gy = gridDim.y, gz = gridDim.z;
  int T = gx * gy * gz;
  int lb = ((int)blockIdx.z * gy + blockIdx.y) * gx + blockIdx.x;
  lb = (lb & 7) * (T >> 3) + (lb >> 3);
  int cob  = lb % gy;
  int n    = (lb / gy) % gz;
  int tile = lb / (gy * gz);
  int lane = threadIdx.x & 63, wave = threadIdx.x >> 6;
  int l15 = lane & 15, lhi = lane >> 4;
  int tiles_x = Wout >> 4;
  int tx = tile % tiles_x, ty = tile / tiles_x;
  int ow0 = tx << 4;
  int oh0 = ty * (4 * TROWS) + wave * TROWS;
  int co0 = cob * 32;
  floatx4 acc[2][TROWS] = {};
  const _Float16* ip = in + (size_t)n * Hin * Win * CIN;
  int x_base = (ow0 + l15) * STRIDE;
  int ybase = oh0 * STRIDE - 1;
  constexpr int NY = (TROWS - 1) * STRIDE + 3;
  const _Float16* wA = wT + (size_t)(co0 + l15) * CIN;
  const _Float16* wB = wT + (size_t)(co0 + 16 + l15) * CIN;
  for (int kc = 0; kc < CIN / 32; kc++) {
    int ci = kc * 32 + lhi * 8;
#pragma unroll
    for (int dxi = 0; dxi < 3; dxi++) {
      int x = x_base + dxi - 1;
      bool xv = (unsigned)x < (unsigned)Win;
      int xc = x < 0 ? 0 : (x >= Win ? Win - 1 : x);
      half8_t a0[3], a1[3];
#pragma unroll
      for (int dy = 0; dy < 3; dy++) {
        int q = dy * 3 + dxi;
        a0[dy] = *(const half8_t*)(wA + (size_t)q * COUT * CIN + ci);
        a1[dy] = *(const half8_t*)(wB + (size_t)q * COUT * CIN + ci);
      }
#pragma unroll
      for (int y6 = 0; y6 < NY; y6++) {
        int y = ybase + y6;
        if ((unsigned)y >= (unsigned)Hin) continue;   // wave-uniform; skip == zero-pad
        half8_t bf = *(const half8_t*)(ip + ((size_t)y * Win + xc) * CIN + ci);
        half8_t z = {};
        bf = xv ? bf : z;
#pragma unroll
        for (int dy = 0; dy < 3; dy++) {
          int tnum = y6 - dy;
          if (tnum < 0 || tnum % STRIDE != 0) continue;
          int t = tnum / STRIDE;
          if (t >= TROWS) continue;
          acc[0][t] = __builtin_amdgcn_mfma_f32_16x16x32_f16(a0[dy], bf, acc[0][t], 0, 0, 0);
          acc[1][t] = __builtin_amdgcn_mfma_f32_16x16x32_f16(a1[dy], bf, acc[1][t], 0, 0, 0);
        }
      }
    }
  }
  float aP = alpha[0];
#pragma unroll
  for (int h = 0; h < 2; h++) {
    float bia[4];
#pragma unroll
    for (int r = 0; r < 4; r++) bia[r] = bias[co0 + h * 16 + lhi * 4 + r];
#pragma unroll
    for (int t = 0; t < TROWS; t++) {
      half4_t hh;
#pragma unroll
      for (int r = 0; r < 4; r++) {
        float v = acc[h][t][r] + bia[r];
        v = v > 0.f ? v : aP * v;
        hh[r] = (_Float16)v;
      }
      *(half4_t*)(outp + (((size_t)n * Hout + oh0 + t) * Wout + ow0 + l15) * COUT +
                  co0 + h * 16 + lhi * 4) = hh;
    }
  }
}

// ---------------- hierarchical scan (atomic-free): part -> apply ----------------
__global__ __launch_bounds__(256) void k_scan_part(
    const unsigned* __restrict__ cnt, unsigned* __restrict__ tpre,
    unsigned* __restrict__ psum) {
  int b = blockIdx.x, t = threadIdx.x;
  int off, sz, ci;
  chunk_map(b, off, sz, ci);
  int base = off + ci * CHUNK + t * 64;
  int lim = off + min(sz, (ci + 1) * CHUNK);
  unsigned s = 0;
  for (int j = 0; j < 64; j++) {
    int idx = base + j;
    if (idx < lim) s += cnt[idx];
  }
  __shared__ unsigned sm[256];
  sm[t] = s;
  __syncthreads();
  for (int o = 1; o < 256; o <<= 1) {
    unsigned v = (t >= o) ? sm[t - o] : 0u;
    __syncthreads();
    sm[t] += v;
    __syncthreads();
  }
  unsigned incl = sm[t];
  tpre[b * 256 + t] = incl - s;        // exclusive
  if (t == 255) psum[b] = incl;
}

__global__ __launch_bounds__(256) void k_scan_apply(
    const unsigned* __restrict__ cnt, const unsigned* __restrict__ tpre,
    const unsigned* __restrict__ psum,
    uint2* __restrict__ cs, unsigned* __restrict__ curs) {
  int b = blockIdx.x, t = threadIdx.x;
  int off, sz, ci;
  chunk_map(b, off, sz, ci);
  __shared__ unsigned cbs;
  if (t == 0) {
    int first = (off == 0) ? 0 : (off == SZ_F ? NCH_F : NCH_F + NCH_H);
    unsigned c = 0;
    for (int k = first; k < first + ci; k++) c += psum[k];
    cbs = c;
  }
  __syncthreads();
  int base = off + ci * CHUNK + t * 64;
  int lim = off + min(sz, (ci + 1) * CHUNK);
  unsigned run = cbs + tpre[b * 256 + t];
  for (int j = 0; j < 64; j++) {
    int idx = base + j;
    if (idx < lim) {
      unsigned c = cnt[idx];
      cs[idx] = make_uint2(run, c);
      curs[idx] = run;
      run += c;
    }
  }
}

// ---------------- pack-at-slot: full res (both dirs, inline mean-sub) ----------------
__global__ __launch_bounds__(256) void k_pack_full(
    const float* __restrict__ img0, const float* __restrict__ img1,
    const float* __restrict__ msum, float invCnt,
    const _Float16* __restrict__ featN,
    const float* __restrict__ s01, const float* __restrict__ s10,
    const float* __restrict__ flowB,
    float* __restrict__ recs, unsigned* __restrict__ curs) {
  constexpr int NCX = W0 + 1;
  int px = blockIdx.x * 256 + threadIdx.x;
  int b = blockIdx.y;
  int dir = blockIdx.z;
  if (px >= HW0) return;
  int nb = dir * B + b;
  float fx = flowB[((size_t)(nb * 2 + 0)) * HW0 + px];
  float fy = flowB[((size_t)(nb * 2 + 1)) * HW0 + px];
  int sw = px % W0, sh = px / W0;
  float tx = (float)sw + fx, ty = (float)sh + fy;
  float x0f = floorf(tx), y0f = floorf(ty);
  int x0 = (int)x0f, y0 = (int)y0f;
  if (x0 < -1 || x0 > W0 - 1 || y0 < -1 || y0 > H0 - 1) return;
  const float* imp = (dir ? img1 : img0) + (size_t)b * 3 * HW0;
  float m = msum[b] * invCnt;
  float im0 = imp[px] - m, im1 = imp[(size_t)HW0 + px] - m, im2 = imp[(size_t)2 * HW0 + px] - m;
  const float* sig = dir ? s10 : s01;
  float sg = sig[(size_t)b * HW0 + px];
  union { floatx4 f4[RS_F / 4]; unsigned u[RS_F]; } r;
  r.u[0] = f2h(im0, im1);
  r.u[1] = f2h(im2, sg);
  const floatx4* fp = (const floatx4*)(featN + ((size_t)nb * HW0 + px) * 32);
  union { floatx4 f; unsigned u[4]; } t;
#pragma unroll
  for (int j = 0; j < 4; j++) {
    t.f = fp[j];
    r.u[2 + 4 * j + 0] = t.u[0]; r.u[2 + 4 * j + 1] = t.u[1];
    r.u[2 + 4 * j + 2] = t.u[2]; r.u[2 + 4 * j + 3] = t.u[3];
  }
  r.u[18] = __float_as_uint(tx - x0f);
  r.u[19] = __float_as_uint(ty - y0f);
  unsigned slot = atomicAdd(&curs[nb * NC_F + (y0 + 1) * NCX + (x0 + 1)], 1u);
  floatx4* o = (floatx4*)(recs + (size_t)slot * RS_F);
#pragma unroll
  for (int j = 0; j < RS_F / 4; j++) o[j] = r.f4[j];
}

// ---------------- pack-at-slot: reduced res (both dirs) ----------------
template <int C, int Hd, int Wd, int RS>
__global__ __launch_bounds__(256) void k_pack_feat(
    const _Float16* __restrict__ featN, const float* __restrict__ flowB,
    float* __restrict__ recs, unsigned* __restrict__ curs) {
  constexpr int HWd = Hd * Wd;
  constexpr int NCX = Wd + 1;
  constexpr int NC  = (Wd + 1) * (Hd + 1);
  int px = blockIdx.x * 256 + threadIdx.x;
  int b = blockIdx.y;
  int dir = blockIdx.z;
  if (px >= HWd) return;
  int nb = dir * B + b;
  float fx = flowB[((size_t)(nb * 2 + 0)) * HWd + px];
  float fy = flowB[((size_t)(nb * 2 + 1)) * HWd + px];
  int sw = px % Wd, sh = px / Wd;
  float tx = (float)sw + fx, ty = (float)sh + fy;
  float x0f = floorf(tx), y0f = floorf(ty);
  int x0 = (int)x0f, y0 = (int)y0f;
  if (x0 < -1 || x0 > Wd - 1 || y0 < -1 || y0 > Hd - 1) return;
  union { floatx4 f4[RS / 4]; unsigned u[RS]; } r;
  const floatx4* fp = (const floatx4*)(featN + ((size_t)nb * HWd + px) * C);
#pragma unroll
  for (int j = 0; j < C / 8; j++) r.f4[j] = fp[j];
  r.u[C / 2]     = __float_as_uint(tx - x0f);
  r.u[C / 2 + 1] = __float_as_uint(ty - y0f);
#pragma unroll
  for (int j = C / 2 + 2; j < RS; j++) r.u[j] = 0;
  unsigned slot = atomicAdd(&curs[nb * NC + (y0 + 1) * NCX + (x0 + 1)], 1u);
  floatx4* o = (floatx4*)(recs + (size_t)slot * RS);
#pragma unroll
  for (int j = 0; j < RS / 4; j++) o[j] = r.f4[j];
}

// ---------------- full-res gather (both dirs, normalization fused) ----------------
__global__ __launch_bounds__(256) void k_warp_gather_full(
    const float* __restrict__ recs, const uint2* __restrict__ cs,
    float* __restrict__ outImg, float* __restrict__ outFeat, float* __restrict__ outSig) {
  constexpr int NCX = W0 + 1;
  int gx = gridDim.x;
  int T = gx * gridDim.y * gridDim.z;
  int lb = ((int)blockIdx.z * gridDim.y + blockIdx.y) * gx + blockIdx.x;
  lb = (lb & 7) * (T >> 3) + (lb >> 3);
  int q = (lb % gx) * 256 + (int)threadIdx.x;
  int b = (lb / gx) % B;
  int dir = lb / (gx * B);
  if (q >= HW0) return;
  int nb = dir * B + b;
  int qx = q % W0, qy = q / W0;
  float acc[36];
#pragma unroll
  for (int c = 0; c < 36; c++) acc[c] = 0.f;
  float dsum = 0.f;
  for (int ky = 0; ky < 2; ky++) {
    int cy = qy - 1 + ky;
    for (int kx = 0; kx < 2; kx++) {
      int cx = qx - 1 + kx;
      uint2 sc = cs[nb * NC_F + (cy + 1) * NCX + (cx + 1)];
      unsigned s0 = sc.x, cn = sc.y;
      for (unsigned s = s0; s < s0 + cn; s++) {
        const floatx4* r4 = (const floatx4*)(recs + (size_t)s * RS_F);
        floatx4 a0 = r4[0], a1 = r4[1], a2 = r4[2], a3 = r4[3], a4 = r4[4];
        union { floatx4 f; unsigned u[4]; } t;
        float ch[36]; float dxf, dyf;
        t.f = a0; h2f(t.u[0], ch[0], ch[1]);   h2f(t.u[1], ch[2], ch[35]);
                  h2f(t.u[2], ch[3], ch[4]);   h2f(t.u[3], ch[5], ch[6]);
        t.f = a1; h2f(t.u[0], ch[7], ch[8]);   h2f(t.u[1], ch[9], ch[10]);
                  h2f(t.u[2], ch[11], ch[12]); h2f(t.u[3], ch[13], ch[14]);
        t.f = a2; h2f(t.u[0], ch[15], ch[16]); h2f(t.u[1], ch[17], ch[18]);
                  h2f(t.u[2], ch[19], ch[20]); h2f(t.u[3], ch[21], ch[22]);
        t.f = a3; h2f(t.u[0], ch[23], ch[24]); h2f(t.u[1], ch[25], ch[26]);
                  h2f(t.u[2], ch[27], ch[28]); h2f(t.u[3], ch[29], ch[30]);
        t.f = a4; h2f(t.u[0], ch[31], ch[32]); h2f(t.u[1], ch[33], ch[34]);
        dxf = __uint_as_float(t.u[2]); dyf = __uint_as_float(t.u[3]);
        float wx = kx ? (1.f - dxf) : dxf;
        float wy = ky ? (1.f - dyf) : dyf;
        float w = wx * wy;
        dsum += w;
#pragma unroll
        for (int c = 0; c < 36; c++) acc[c] += w * ch[c];
      }
    }
  }
  float inv = 1.f / fmaxf(dsum, 1e-7f);
#pragma unroll
  for (int c = 0; c < 3; c++)
    outImg[((size_t)(b * 6 + dir * 3 + c)) * HW0 + q] = acc[c] * inv;
#pragma unroll
  for (int c = 0; c < 32; c++)
    outFeat[((size_t)(b * 64 + dir * 32 + c)) * HW0 + q] = acc[3 + c] * inv;
  outSig[((size_t)(b * 2 + dir)) * HW0 + q] = acc[35] * inv;
}

// ---------------- reduced-res gather (both dirs x Z chunks, normalization fused) ----------------
template <int C, int Hd, int Wd, int RS, int Z>
__global__ __launch_bounds__(256) void k_warp_gather_feat(
    const float* __restrict__ recs, const uint2* __restrict__ cs,
    float* __restrict__ outF) {
  constexpr int HWd = Hd * Wd;
  constexpr int NCX = Wd + 1;
  constexpr int NC  = (Wd + 1) * (Hd + 1);
  int gx = gridDim.x;
  int T = gx * gridDim.y * gridDim.z;
  int lb = ((int)blockIdx.z * gridDim.y + blockIdx.y) * gx + blockIdx.x;
  lb = (lb & 7) * (T >> 3) + (lb >> 3);
  int q = (lb % gx) * 256 + (int)threadIdx.x;
  int b = (lb / gx) % B;
  int dz = lb / (gx * B);
  int z = dz % Z, dir = dz / Z;
  int c0 = z * 32;
  if (q >= HWd) return;
  int nb = dir * B + b;
  int qx = q % Wd, qy = q / Wd;
  float acc[32];
#pragma unroll
  for (int c = 0; c < 32; c++) acc[c] = 0.f;
  float dsum = 0.f;
  for (int ky = 0; ky < 2; ky++) {
    int cy = qy - 1 + ky;
    for (int kx = 0; kx < 2; kx++) {
      int cx = qx - 1 + kx;
      uint2 sc = cs[nb * NC + (cy + 1) * NCX + (cx + 1)];
      unsigned s0 = sc.x, cn = sc.y;
      for (unsigned s = s0; s < s0 + cn; s++) {
        const unsigned* rp = (const unsigned*)(recs + (size_t)s * RS);
        const floatx4* r4 = (const floatx4*)rp;
        floatx4 a0 = r4[4 * z + 0], a1 = r4[4 * z + 1], a2 = r4[4 * z + 2], a3 = r4[4 * z + 3];
        float2 hd = *(const float2*)(rp + C / 2);
        union { floatx4 f; unsigned u[4]; } t;
        float ch[32];
        t.f = a0; h2f(t.u[0], ch[0], ch[1]);  h2f(t.u[1], ch[2], ch[3]);
                  h2f(t.u[2], ch[4], ch[5]);  h2f(t.u[3], ch[6], ch[7]);
        t.f = a1; h2f(t.u[0], ch[8], ch[9]);  h2f(t.u[1], ch[10], ch[11]);
                  h2f(t.u[2], ch[12], ch[13]);h2f(t.u[3], ch[14], ch[15]);
        t.f = a2; h2f(t.u[0], ch[16], ch[17]);h2f(t.u[1], ch[18], ch[19]);
                  h2f(t.u[2], ch[20], ch[21]);h2f(t.u[3], ch[22], ch[23]);
        t.f = a3; h2f(t.u[0], ch[24], ch[25]);h2f(t.u[1], ch[26], ch[27]);
                  h2f(t.u[2], ch[28], ch[29]);h2f(t.u[3], ch[30], ch[31]);
        float dxf = hd.x, dyf = hd.y;
        float wx = kx ? (1.f - dxf) : dxf;
        float wy = ky ? (1.f - dyf) : dyf;
        float w = wx * wy;
        dsum += w;
#pragma unroll
        for (int c = 0; c < 32; c++) acc[c] += w * ch[c];
      }
    }
  }
  float inv = 1.f / fmaxf(dsum, 1e-7f);
  size_t obase = ((size_t)(b * 2 * C + dir * C + c0)) * HWd + q;
#pragma unroll
  for (int c = 0; c < 32; c++) outF[obase + (size_t)c * HWd] = acc[c] * inv;
}

extern "C" void kernel_launch(void* const* d_in, const int* in_sizes, int n_in,
                              void* d_out, int out_size, void* d_ws, size_t ws_size,
                              hipStream_t stream) {
  (void)in_sizes; (void)n_in; (void)out_size;
  if (ws_size < WS_FLOATS * sizeof(float)) return;

  const float* img0    = (const float*)d_in[0];
  const float* img1    = (const float*)d_in[1];
  const float* flow01  = (const float*)d_in[2];
  const float* sigma01 = (const float*)d_in[3];
  const float* flow10  = (const float*)d_in[4];
  const float* sigma10 = (const float*)d_in[5];
  const float* wp[6]; const float* bp[6]; const float* ap[6];
  for (int i = 0; i < 6; i++) {
    wp[i] = (const float*)(d_in[6 + 3 * i]);
    bp[i] = (const float*)(d_in[7 + 3 * i]);
    ap[i] = (const float*)(d_in[8 + 3 * i]);
  }
  float* ws  = (float*)d_ws;
  float* out = (float*)d_out;

  unsigned* cntAll  = (unsigned*)(ws + OFF_CNT);
  unsigned* cntF = cntAll;
  unsigned* cntH = cntAll + SZ_F;
  unsigned* cntQ = cntAll + SZ_F + SZ_H;
  uint2*    csAll = (uint2*)(ws + OFF_CS);
  uint2*    csF = csAll, *csH = csAll + SZ_F, *csQ = csAll + SZ_F + SZ_H;
  unsigned* cursAll  = (unsigned*)(ws + OFF_CURS);
  unsigned* cursF = cursAll, *cursH = cursAll + SZ_F, *cursQ = cursAll + SZ_F + SZ_H;
  unsigned* tpre  = (unsigned*)(ws + OFF_TPRE);
  unsigned* psum  = (unsigned*)(ws + OFF_PSUM);
  float*    recs    = ws + OFF_RECS;
  _Float16* Ah = (_Float16*)(ws + OFF_BUFA);
  _Float16* Bh = (_Float16*)(ws + OFF_BUFB);
  _Float16* wt[5] = {(_Float16*)(ws + OFF_WT2), (_Float16*)(ws + OFF_WT3),
                     (_Float16*)(ws + OFF_WT4), (_Float16*)(ws + OFF_WT5),
                     (_Float16*)(ws + OFF_WT6)};
  float* flowF = ws + OFF_FLOW;
  float* flowH = ws + OFF_FLH;
  float* flowQ = ws + OFF_FLQ;

  const float invCnt = 1.f / (6.f * (float)HW0);

  // single upfront zero: mean + all cnt regions (~4.9 MB)
  hipMemsetAsync(ws, 0, ZERO_FLOATS * sizeof(float), stream);

  dim3 blk(256);

  k_wtrans_all<<<dim3((202752 + 255) / 256), blk, 0, stream>>>(
      wp[1], wp[2], wp[3], wp[4], wp[5], wt[0], wt[1], wt[2], wt[3], wt[4]);

  k_mean<<<dim3(32, B), blk, 0, stream>>>(img0, img1, ws + OFF_MEAN, 3 * HW0);

  // flows + fused counts
  k_interflow2<<<dim3((2 * B * HW0 + 255) / 256), blk, 0, stream>>>(
      flow01, sigma01, flow10, sigma10, flowF, cntF);
  k_downflow2<2, H1, W1><<<dim3((2 * B * HW1 + 255) / 256), blk, 0, stream>>>(
      flowF, flowH, cntH);
  k_downflow2<4, H2, W2><<<dim3((2 * B * HW2 + 255) / 256), blk, 0, stream>>>(
      flowF, flowQ, cntQ);

  // atomic-free hierarchical scan over all 3 regions (2 dispatches)
  k_scan_part<<<dim3(NCHUNKS), blk, 0, stream>>>(cntAll, tpre, psum);
  k_scan_apply<<<dim3(NCHUNKS), blk, 0, stream>>>(cntAll, tpre, psum, csAll, cursAll);

  // conv1 (8 batches, all 32 co, inline mean-sub) -> Ah ; conv2 -> Bh = f01
  conv1_nhwc<<<dim3(7 * 64, 1, 8), blk, 0, stream>>>(
      img0, img1, ws + OFF_MEAN, invCnt, wp[0], bp[0], ap[0], Ah);
  conv_mfma<32, 32, 1, 8><<<dim3(28 * 8, 1, 8), blk, 0, stream>>>(
      Ah, wt[0], bp[1], ap[1], Bh, H0, W0, H0, W0);

  // full-res warp (both dirs): pack-at-slot -> gather
  k_pack_full<<<dim3(HW0 / 256, B, 2), blk, 0, stream>>>(
      img0, img1, ws + OFF_MEAN, invCnt, Bh, sigma01, sigma10, flowF, recs, cursF);
  k_warp_gather_full<<<dim3(HW0 / 256, B, 2), blk, 0, stream>>>(
      recs, csF, out + O_IMG, out + O_F1, out + O_SIG);

  // conv3 s2 -> Ah ; conv4 -> Bh = f02
  conv_mfma<32, 64, 2, 4><<<dim3(14 * 8, 2, 8), blk, 0, stream>>>(
      Bh, wt[1], bp[2], ap[2], Ah, H0, W0, H1, W1);
  conv_mfma<64, 64, 1, 8><<<dim3(14 * 4, 2, 8), blk, 0, stream>>>(
      Ah, wt[2], bp[3], ap[3], Bh, H1, W1, H1, W1);

  k_pack_feat<64, H1, W1, RS_H><<<dim3(HW1 / 256, B, 2), blk, 0, stream>>>(
      Bh, flowH, recs, cursH);
  k_warp_gather_feat<64, H1, W1, RS_H, 2><<<dim3(HW1 / 256, B, 4), blk, 0, stream>>>(
      recs, csH, out + O_F2);

  // conv5 s2 -> Ah ; conv6 -> Bh = f03
  conv_mfma<64, 96, 2, 4><<<dim3(7 * 4, 3, 8), blk, 0, stream>>>(
      Bh, wt[3], bp[4], ap[4], Ah, H1, W1, H2, W2);
  conv_mfma<96, 96, 1, 4><<<dim3(7 * 4, 3, 8), blk, 0, stream>>>(
      Ah, wt[4], bp[5], ap[5], Bh, H2, W2, H2, W2);

  k_pack_feat<96, H2, W2, RS_Q><<<dim3(HW2 / 256, B, 2), blk, 0, stream>>>(
      Bh, flowQ, recs, cursQ);
  k_warp_gather_feat<96, H2, W2, RS_Q, 3><<<dim3(HW2 / 256, B, 6), blk, 0, stream>>>(
      recs, csQ, out + O_F3);
}

// Round 13
// 573.586 us; speedup vs baseline: 1.1790x; 1.1225x over previous
//
#include <hip/hip_runtime.h>
#include <hip/hip_fp16.h>

static constexpr int B  = 4;
static constexpr int H0 = 256, W0 = 448, HW0 = H0 * W0;   // full
static constexpr int H1 = 128, W1 = 224, HW1 = H1 * W1;   // half
static constexpr int H2 = 64,  W2 = 112, HW2 = H2 * W2;   // quarter

typedef _Float16 half8_t __attribute__((ext_vector_type(8)));
typedef _Float16 half4_t __attribute__((ext_vector_type(4)));
typedef float floatx4 __attribute__((ext_vector_type(4)));

static constexpr int NC_F = (W0 + 1) * (H0 + 1);
static constexpr int NC_H = (W1 + 1) * (H1 + 1);
static constexpr int NC_Q = (W2 + 1) * (H2 + 1);

static constexpr int RS_F = 20;
static constexpr int RS_H = 36;
static constexpr int RS_Q = 52;

static constexpr int SZ_F = 2 * B * NC_F;
static constexpr int SZ_H = 2 * B * NC_H;
static constexpr int SZ_Q = 2 * B * NC_Q;
static constexpr int CNT_TOTAL = SZ_F + SZ_H + SZ_Q;

static constexpr int CHUNK = 16384;
static constexpr int NCH_F = (SZ_F + CHUNK - 1) / CHUNK;
static constexpr int NCH_H = (SZ_H + CHUNK - 1) / CHUNK;
static constexpr int NCH_Q = (SZ_Q + CHUNK - 1) / CHUNK;
static constexpr int NCHUNKS = NCH_F + NCH_H + NCH_Q;     // 76

// ---------------- workspace layout (floats) ----------------
static constexpr size_t OFF_MEAN   = 0;
static constexpr size_t OFF_CNT    = 256;
static constexpr size_t ZERO_FLOATS = OFF_CNT + CNT_TOTAL;
static constexpr size_t OFF_BUFA   = ZERO_FLOATS;
static constexpr size_t OFF_BUFB   = OFF_BUFA + (size_t)4 * 32 * HW0;
static constexpr size_t OFF_FLOW   = OFF_BUFB + (size_t)4 * 32 * HW0;
static constexpr size_t OFF_FLH    = OFF_FLOW + (size_t)2 * B * 2 * HW0;
static constexpr size_t OFF_FLQ    = OFF_FLH + (size_t)2 * B * 2 * HW1;
static constexpr size_t OFF_WT2 = OFF_FLQ + (size_t)2 * B * 2 * HW2;
static constexpr size_t OFF_WT3 = OFF_WT2 + 4608;
static constexpr size_t OFF_WT4 = OFF_WT3 + 9216;
static constexpr size_t OFF_WT5 = OFF_WT4 + 18432;
static constexpr size_t OFF_WT6 = OFF_WT5 + 27648;
static constexpr size_t OFF_CS   = OFF_WT6 + 41472;
static constexpr size_t OFF_CURS = OFF_CS + (size_t)2 * CNT_TOTAL;
static constexpr size_t OFF_TPRE = OFF_CURS + CNT_TOTAL;
static constexpr size_t OFF_PSUM = OFF_TPRE + (size_t)NCHUNKS * 256;
static constexpr size_t OFF_RECS = OFF_PSUM + 128;
static constexpr size_t WS_FLOATS = OFF_RECS + (size_t)2 * B * HW0 * RS_F;

// ---------------- output layout (floats) ----------------
static constexpr size_t O_IMG = 0;
static constexpr size_t O_F1  = O_IMG + (size_t)B * 6 * HW0;
static constexpr size_t O_F2  = O_F1  + (size_t)B * 64 * HW0;
static constexpr size_t O_F3  = O_F2  + (size_t)B * 128 * HW1;
static constexpr size_t O_SIG = O_F3  + (size_t)B * 192 * HW2;

// sub-grid block counts (all multiples of 8 -> bijective XCD swizzle)
static constexpr int NB_IF = 2 * B * HW0 / 256;   // 3584
static constexpr int NB_MEAN = 32 * B;            // 128
static constexpr int NB_WT = (202752 + 255) / 256;// 792
static constexpr int NB_DH = 2 * B * HW1 / 256;   // 896
static constexpr int NB_DQ = 2 * B * HW2 / 256;   // 224
static constexpr int NB_C1 = 448 * 8;             // 3584
static constexpr int NB_C2 = 224 * 8;             // 1792
static constexpr int NB_PF = (HW0 / 256) * B * 2; // 3584
static constexpr int NB_C3 = 112 * 2 * 8;         // 1792
static constexpr int NB_GF = NB_PF;               // 3584
static constexpr int NB_C4 = 56 * 2 * 8;          // 896
static constexpr int NB_PH = (HW1 / 256) * B * 2; // 896
static constexpr int NB_C5 = 28 * 3 * 8;          // 672
static constexpr int NB_GH = (HW1 / 256) * B * 4; // 1792
static constexpr int NB_C6 = 28 * 3 * 8;          // 672

__device__ inline void h2f(unsigned u, float& lo, float& hi) {
  __half2 h = *reinterpret_cast<__half2*>(&u);
  float2 f = __half22float2(h);
  lo = f.x; hi = f.y;
}
__device__ inline unsigned f2h(float lo, float hi) {
  __half2 h = __floats2half2_rn(lo, hi);
  return *reinterpret_cast<unsigned*>(&h);
}

__device__ inline void chunk_map(int b, int& off, int& sz, int& ci) {
  if (b < NCH_F)              { off = 0;           sz = SZ_F; ci = b; }
  else if (b < NCH_F + NCH_H) { off = SZ_F;        sz = SZ_H; ci = b - NCH_F; }
  else                        { off = SZ_F + SZ_H; sz = SZ_Q; ci = b - NCH_F - NCH_H; }
}

// ================= device bodies =================

__device__ __forceinline__ void d_mean(const float* __restrict__ img0,
                                       const float* __restrict__ img1,
                                       float* __restrict__ msum, int s) {
  const int perImg = 3 * HW0;
  int bx = s & 31, b = s >> 5;
  float acc = 0.f;
  int tot = 2 * perImg;
  for (int i = bx * 256 + threadIdx.x; i < tot; i += 32 * 256) {
    acc += (i < perImg) ? img0[(size_t)b * perImg + i] : img1[(size_t)b * perImg + (i - perImg)];
  }
#pragma unroll
  for (int o = 32; o > 0; o >>= 1) acc += __shfl_down(acc, o);
  __shared__ float red[4];
  int lane = threadIdx.x & 63, wid = threadIdx.x >> 6;
  if (lane == 0) red[wid] = acc;
  __syncthreads();
  if (threadIdx.x == 0) atomicAdd(&msum[b], red[0] + red[1] + red[2] + red[3]);
}

__device__ __forceinline__ void d_interflow2(
    const float* __restrict__ f01, const float* __restrict__ s01,
    const float* __restrict__ f10, const float* __restrict__ s10,
    float* __restrict__ outBase, unsigned* __restrict__ cntF, int s) {
  constexpr int NCX = W0 + 1;
  int i = s * 256 + (int)threadIdx.x;
  if (i >= 2 * B * HW0) return;
  int nb = i / HW0;
  int px = i - nb * HW0;
  int dir = nb >> 2, b = nb & 3;
  const float* flo = dir ? f10 : f01;
  const float* sigma = dir ? s10 : s01;
  float fx = flo[((size_t)(b * 2 + 0)) * HW0 + px];
  float fy = flo[((size_t)(b * 2 + 1)) * HW0 + px];
  float sg = sigma[(size_t)b * HW0 + px];
  float ftx, fty;
  if (fabsf(sg) < 0.01f) {
    ftx = 0.5f * fx; fty = 0.5f * fy;
  } else {
    float g = (1.f - sqrtf(fmaxf(0.f, 1.f - sg * sg))) / (2.f * sg);
    ftx = 0.5f * fx - g * fy;
    fty = 0.5f * fy + g * fx;
  }
  outBase[((size_t)(nb * 2 + 0)) * HW0 + px] = ftx;
  outBase[((size_t)(nb * 2 + 1)) * HW0 + px] = fty;
  int sw = px % W0, sh = px / W0;
  float tx = (float)sw + ftx, ty = (float)sh + fty;
  int x0 = (int)floorf(tx), y0 = (int)floorf(ty);
  if (x0 >= -1 && x0 <= W0 - 1 && y0 >= -1 && y0 <= H0 - 1)
    atomicAdd(&cntF[nb * NC_F + (y0 + 1) * NCX + (x0 + 1)], 1u);
}

template <int F, int Hd, int Wd>
__device__ __forceinline__ void d_downflow2(
    const float* __restrict__ in, float* __restrict__ out,
    unsigned* __restrict__ cnt, int s) {
  constexpr int HWd = Hd * Wd;
  constexpr int NCX = Wd + 1;
  constexpr int NC  = (Wd + 1) * (Hd + 1);
  int i = s * 256 + (int)threadIdx.x;
  if (i >= 2 * B * HWd) return;
  int nb = i / HWd;
  int px = i - nb * HWd;
  int ow = px % Wd, oh = px / Wd;
  float cy = (oh + 0.5f) * F - 0.5f;
  float cx = (ow + 0.5f) * F - 0.5f;
  int ylo = (int)floorf(cy) - F + 1;
  int xlo = (int)floorf(cx) - F + 1;
  const float* ipx = in + ((size_t)(nb * 2 + 0)) * HW0;
  const float* ipy = in + ((size_t)(nb * 2 + 1)) * HW0;
  float ax = 0.f, ay = 0.f, wn = 0.f;
  for (int jy = 0; jy < 2 * F; jy++) {
    int y = ylo + jy;
    if ((unsigned)y >= (unsigned)H0) continue;
    float wy = 1.f - fabsf((float)y - cy) / (float)F;
    for (int jx = 0; jx < 2 * F; jx++) {
      int x = xlo + jx;
      if ((unsigned)x >= (unsigned)W0) continue;
      float wx = 1.f - fabsf((float)x - cx) / (float)F;
      float ww = wy * wx;
      ax += ww * ipx[(size_t)y * W0 + x];
      ay += ww * ipy[(size_t)y * W0 + x];
      wn += ww;
    }
  }
  float sc = 1.f / (wn * (float)F);
  float fx = ax * sc, fy = ay * sc;
  out[((size_t)(nb * 2 + 0)) * HWd + px] = fx;
  out[((size_t)(nb * 2 + 1)) * HWd + px] = fy;
  float tx = (float)ow + fx, ty = (float)oh + fy;
  int x0 = (int)floorf(tx), y0 = (int)floorf(ty);
  if (x0 >= -1 && x0 <= Wd - 1 && y0 >= -1 && y0 <= Hd - 1)
    atomicAdd(&cnt[nb * NC + (y0 + 1) * NCX + (x0 + 1)], 1u);
}

__device__ __forceinline__ void d_wtrans(
    const float* __restrict__ w2, const float* __restrict__ w3,
    const float* __restrict__ w4, const float* __restrict__ w5,
    const float* __restrict__ w6,
    _Float16* __restrict__ o2, _Float16* __restrict__ o3,
    _Float16* __restrict__ o4, _Float16* __restrict__ o5,
    _Float16* __restrict__ o6, int s) {
  int i = s * 256 + (int)threadIdx.x;
  const float* w; _Float16* o; int COUT, CIN, base;
  if      (i <   9216) { w = w2; o = o2; COUT = 32; CIN = 32; base = 0; }
  else if (i <  27648) { w = w3; o = o3; COUT = 64; CIN = 32; base = 9216; }
  else if (i <  64512) { w = w4; o = o4; COUT = 64; CIN = 64; base = 27648; }
  else if (i < 119808) { w = w5; o = o5; COUT = 96; CIN = 64; base = 64512; }
  else if (i < 202752) { w = w6; o = o6; COUT = 96; CIN = 96; base = 119808; }
  else return;
  int j = i - base;
  int q = j % 9;
  int rest = j / 9;
  int ci = rest % CIN;
  int co = rest / CIN;
  o[((size_t)q * COUT + co) * CIN + ci] = (_Float16)w[j];
}

__device__ __forceinline__ void d_conv1(
    const float* __restrict__ img0, const float* __restrict__ img1,
    const float* __restrict__ msum, float invCnt,
    const float* __restrict__ wgt, const float* __restrict__ bias,
    const float* __restrict__ alpha, _Float16* __restrict__ outp, int s) {
  __shared__ float wsm[32 * 27];
  __shared__ float bsm[32];
  int bx = s % 448, n = s / 448;
  for (int i = threadIdx.x; i < 32 * 27; i += 256) wsm[i] = wgt[i];
  if (threadIdx.x < 32) bsm[threadIdx.x] = bias[threadIdx.x];
  __syncthreads();
  int b = n & 3;
  const float* ip = (n < 4 ? img0 : img1) + (size_t)b * 3 * HW0;
  float m = msum[b] * invCnt;
  int tx = bx % 7, ty = bx / 7;
  int ow = tx * 64 + (threadIdx.x & 63);
  int oh = ty * 4 + (threadIdx.x >> 6);
  float xv[27];
#pragma unroll
  for (int ci = 0; ci < 3; ci++) {
    const float* iq = ip + (size_t)ci * HW0;
#pragma unroll
    for (int ky = 0; ky < 3; ky++) {
      int y = oh - 1 + ky;
      bool yv = (unsigned)y < (unsigned)H0;
      const float* row = iq + (size_t)y * W0;
#pragma unroll
      for (int kx = 0; kx < 3; kx++) {
        int x = ow - 1 + kx;
        xv[ci * 9 + ky * 3 + kx] = (yv && (unsigned)x < (unsigned)W0) ? row[x] - m : 0.f;
      }
    }
  }
  float a = alpha[0];
  _Float16* ob = outp + ((size_t)(n * H0 + oh) * W0 + ow) * 32;
#pragma clang loop unroll(disable)
  for (int g = 0; g < 4; g++) {
    float acc[8];
#pragma unroll
    for (int k = 0; k < 8; k++) acc[k] = bsm[g * 8 + k];
#pragma unroll
    for (int k = 0; k < 8; k++) {
      const float* wp = &wsm[(g * 8 + k) * 27];
#pragma unroll
      for (int j = 0; j < 27; j++) acc[k] += xv[j] * wp[j];
    }
    half8_t h;
#pragma unroll
    for (int k = 0; k < 8; k++) {
      float v = acc[k];
      v = v > 0.f ? v : a * v;
      h[k] = (_Float16)v;
    }
    *(half8_t*)(ob + g * 8) = h;
  }
}

template <int CIN, int COUT, int STRIDE, int TROWS>
__device__ __forceinline__ void conv_mfma_body(
    const _Float16* __restrict__ in, const _Float16* __restrict__ wT,
    const float* __restrict__ bias, const float* __restrict__ alpha,
    _Float16* __restrict__ outp, int Hin, int Win, int Hout, int Wout,
    int gx, int gy, int gz, int lb) {
  int T = gx * gy * gz;
  lb = (lb & 7) * (T >> 3) + (lb >> 3);
  int cob  = lb % gy;
  int n    = (lb / gy) % gz;
  int tile = lb / (gy * gz);
  int lane = threadIdx.x & 63, wave = threadIdx.x >> 6;
  int l15 = lane & 15, lhi = lane >> 4;
  int tiles_x = Wout >> 4;
  int tx = tile % tiles_x, ty = tile / tiles_x;
  int ow0 = tx << 4;
  int oh0 = ty * (4 * TROWS) + wave * TROWS;
  int co0 = cob * 32;
  floatx4 acc[2][TROWS] = {};
  const _Float16* ip = in + (size_t)n * Hin * Win * CIN;
  int x_base = (ow0 + l15) * STRIDE;
  int ybase = oh0 * STRIDE - 1;
  constexpr int NY = (TROWS - 1) * STRIDE + 3;
  const _Float16* wA = wT + (size_t)(co0 + l15) * CIN;
  const _Float16* wB = wT + (size_t)(co0 + 16 + l15) * CIN;
  for (int kc = 0; kc < CIN / 32; kc++) {
    int ci = kc * 32 + lhi * 8;
#pragma unroll
    for (int dxi = 0; dxi < 3; dxi++) {
      int x = x_base + dxi - 1;
      bool xv = (unsigned)x < (unsigned)Win;
      int xc = x < 0 ? 0 : (x >= Win ? Win - 1 : x);
      half8_t a0[3], a1[3];
#pragma unroll
      for (int dy = 0; dy < 3; dy++) {
        int q = dy * 3 + dxi;
        a0[dy] = *(const half8_t*)(wA + (size_t)q * COUT * CIN + ci);
        a1[dy] = *(const half8_t*)(wB + (size_t)q * COUT * CIN + ci);
      }
#pragma unroll
      for (int y6 = 0; y6 < NY; y6++) {
        int y = ybase + y6;
        if ((unsigned)y >= (unsigned)Hin) continue;   // wave-uniform; skip == zero-pad
        half8_t bf = *(const half8_t*)(ip + ((size_t)y * Win + xc) * CIN + ci);
        half8_t z = {};
        bf = xv ? bf : z;
#pragma unroll
        for (int dy = 0; dy < 3; dy++) {
          int tnum = y6 - dy;
          if (tnum < 0 || tnum % STRIDE != 0) continue;
          int t = tnum / STRIDE;
          if (t >= TROWS) continue;
          acc[0][t] = __builtin_amdgcn_mfma_f32_16x16x32_f16(a0[dy], bf, acc[0][t], 0, 0, 0);
          acc[1][t] = __builtin_amdgcn_mfma_f32_16x16x32_f16(a1[dy], bf, acc[1][t], 0, 0, 0);
        }
      }
    }
  }
  float aP = alpha[0];
#pragma unroll
  for (int h = 0; h < 2; h++) {
    float bia[4];
#pragma unroll
    for (int r = 0; r < 4; r++) bia[r] = bias[co0 + h * 16 + lhi * 4 + r];
#pragma unroll
    for (int t = 0; t < TROWS; t++) {
      half4_t hh;
#pragma unroll
      for (int r = 0; r < 4; r++) {
        float v = acc[h][t][r] + bia[r];
        v = v > 0.f ? v : aP * v;
        hh[r] = (_Float16)v;
      }
      *(half4_t*)(outp + (((size_t)n * Hout + oh0 + t) * Wout + ow0 + l15) * COUT +
                  co0 + h * 16 + lhi * 4) = hh;
    }
  }
}

__device__ __forceinline__ void d_scan_part(
    const unsigned* __restrict__ cnt, unsigned* __restrict__ tpre,
    unsigned* __restrict__ psum, int b) {
  int t = threadIdx.x;
  int off, sz, ci;
  chunk_map(b, off, sz, ci);
  int base = off + ci * CHUNK + t * 64;
  int lim = off + min(sz, (ci + 1) * CHUNK);
  unsigned s = 0;
  for (int j = 0; j < 64; j++) {
    int idx = base + j;
    if (idx < lim) s += cnt[idx];
  }
  __shared__ unsigned sm[256];
  sm[t] = s;
  __syncthreads();
  for (int o = 1; o < 256; o <<= 1) {
    unsigned v = (t >= o) ? sm[t - o] : 0u;
    __syncthreads();
    sm[t] += v;
    __syncthreads();
  }
  unsigned incl = sm[t];
  tpre[b * 256 + t] = incl - s;
  if (t == 255) psum[b] = incl;
}

__device__ __forceinline__ void pack_full_body(
    const float* __restrict__ img0, const float* __restrict__ img1,
    const float* __restrict__ msum, float invCnt,
    const _Float16* __restrict__ featN,
    const float* __restrict__ s01, const float* __restrict__ s10,
    const float* __restrict__ flowB,
    float* __restrict__ recs, unsigned* __restrict__ curs, int s) {
  constexpr int NCX = W0 + 1;
  constexpr int GX = HW0 / 256;
  int px = (s % GX) * 256 + (int)threadIdx.x;
  int b = (s / GX) % B;
  int dir = s / (GX * B);
  int nb = dir * B + b;
  float fx = flowB[((size_t)(nb * 2 + 0)) * HW0 + px];
  float fy = flowB[((size_t)(nb * 2 + 1)) * HW0 + px];
  int sw = px % W0, sh = px / W0;
  float tx = (float)sw + fx, ty = (float)sh + fy;
  float x0f = floorf(tx), y0f = floorf(ty);
  int x0 = (int)x0f, y0 = (int)y0f;
  if (x0 < -1 || x0 > W0 - 1 || y0 < -1 || y0 > H0 - 1) return;
  const float* imp = (dir ? img1 : img0) + (size_t)b * 3 * HW0;
  float m = msum[b] * invCnt;
  float im0 = imp[px] - m, im1 = imp[(size_t)HW0 + px] - m, im2 = imp[(size_t)2 * HW0 + px] - m;
  const float* sig = dir ? s10 : s01;
  float sg = sig[(size_t)b * HW0 + px];
  union { floatx4 f4[RS_F / 4]; unsigned u[RS_F]; } r;
  r.u[0] = f2h(im0, im1);
  r.u[1] = f2h(im2, sg);
  const floatx4* fp = (const floatx4*)(featN + ((size_t)nb * HW0 + px) * 32);
  union { floatx4 f; unsigned u[4]; } t;
#pragma unroll
  for (int j = 0; j < 4; j++) {
    t.f = fp[j];
    r.u[2 + 4 * j + 0] = t.u[0]; r.u[2 + 4 * j + 1] = t.u[1];
    r.u[2 + 4 * j + 2] = t.u[2]; r.u[2 + 4 * j + 3] = t.u[3];
  }
  r.u[18] = __float_as_uint(tx - x0f);
  r.u[19] = __float_as_uint(ty - y0f);
  unsigned slot = atomicAdd(&curs[nb * NC_F + (y0 + 1) * NCX + (x0 + 1)], 1u);
  floatx4* o = (floatx4*)(recs + (size_t)slot * RS_F);
#pragma unroll
  for (int j = 0; j < RS_F / 4; j++) o[j] = r.f4[j];
}

template <int C, int Hd, int Wd, int RS>
__device__ __forceinline__ void pack_feat_body(
    const _Float16* __restrict__ featN, const float* __restrict__ flowB,
    float* __restrict__ recs, unsigned* __restrict__ curs, int s) {
  constexpr int HWd = Hd * Wd;
  constexpr int NCX = Wd + 1;
  constexpr int NC  = (Wd + 1) * (Hd + 1);
  constexpr int GX = HWd / 256;
  int px = (s % GX) * 256 + (int)threadIdx.x;
  int b = (s / GX) % B;
  int dir = s / (GX * B);
  int nb = dir * B + b;
  float fx = flowB[((size_t)(nb * 2 + 0)) * HWd + px];
  float fy = flowB[((size_t)(nb * 2 + 1)) * HWd + px];
  int sw = px % Wd, sh = px / Wd;
  float tx = (float)sw + fx, ty = (float)sh + fy;
  float x0f = floorf(tx), y0f = floorf(ty);
  int x0 = (int)x0f, y0 = (int)y0f;
  if (x0 < -1 || x0 > Wd - 1 || y0 < -1 || y0 > Hd - 1) return;
  union { floatx4 f4[RS / 4]; unsigned u[RS]; } r;
  const floatx4* fp = (const floatx4*)(featN + ((size_t)nb * HWd + px) * C);
#pragma unroll
  for (int j = 0; j < C / 8; j++) r.f4[j] = fp[j];
  r.u[C / 2]     = __float_as_uint(tx - x0f);
  r.u[C / 2 + 1] = __float_as_uint(ty - y0f);
#pragma unroll
  for (int j = C / 2 + 2; j < RS; j++) r.u[j] = 0;
  unsigned slot = atomicAdd(&curs[nb * NC + (y0 + 1) * NCX + (x0 + 1)], 1u);
  floatx4* o = (floatx4*)(recs + (size_t)slot * RS);
#pragma unroll
  for (int j = 0; j < RS / 4; j++) o[j] = r.f4[j];
}

__device__ __forceinline__ void gather_full_body(
    const float* __restrict__ recs, const uint2* __restrict__ cs,
    float* __restrict__ outImg, float* __restrict__ outFeat,
    float* __restrict__ outSig, int lb) {
  constexpr int NCX = W0 + 1;
  constexpr int GX = HW0 / 256;
  constexpr int T = GX * B * 2;
  lb = (lb & 7) * (T >> 3) + (lb >> 3);
  int q = (lb % GX) * 256 + (int)threadIdx.x;
  int b = (lb / GX) % B;
  int dir = lb / (GX * B);
  int nb = dir * B + b;
  int qx = q % W0, qy = q / W0;
  float acc[36];
#pragma unroll
  for (int c = 0; c < 36; c++) acc[c] = 0.f;
  float dsum = 0.f;
  for (int ky = 0; ky < 2; ky++) {
    int cy = qy - 1 + ky;
    for (int kx = 0; kx < 2; kx++) {
      int cx = qx - 1 + kx;
      uint2 sc = cs[nb * NC_F + (cy + 1) * NCX + (cx + 1)];
      unsigned s0 = sc.x, cn = sc.y;
      for (unsigned s = s0; s < s0 + cn; s++) {
        const floatx4* r4 = (const floatx4*)(recs + (size_t)s * RS_F);
        floatx4 a0 = r4[0], a1 = r4[1], a2 = r4[2], a3 = r4[3], a4 = r4[4];
        union { floatx4 f; unsigned u[4]; } t;
        float ch[36]; float dxf, dyf;
        t.f = a0; h2f(t.u[0], ch[0], ch[1]);   h2f(t.u[1], ch[2], ch[35]);
                  h2f(t.u[2], ch[3], ch[4]);   h2f(t.u[3], ch[5], ch[6]);
        t.f = a1; h2f(t.u[0], ch[7], ch[8]);   h2f(t.u[1], ch[9], ch[10]);
                  h2f(t.u[2], ch[11], ch[12]); h2f(t.u[3], ch[13], ch[14]);
        t.f = a2; h2f(t.u[0], ch[15], ch[16]); h2f(t.u[1], ch[17], ch[18]);
                  h2f(t.u[2], ch[19], ch[20]); h2f(t.u[3], ch[21], ch[22]);
        t.f = a3; h2f(t.u[0], ch[23], ch[24]); h2f(t.u[1], ch[25], ch[26]);
                  h2f(t.u[2], ch[27], ch[28]); h2f(t.u[3], ch[29], ch[30]);
        t.f = a4; h2f(t.u[0], ch[31], ch[32]); h2f(t.u[1], ch[33], ch[34]);
        dxf = __uint_as_float(t.u[2]); dyf = __uint_as_float(t.u[3]);
        float wx = kx ? (1.f - dxf) : dxf;
        float wy = ky ? (1.f - dyf) : dyf;
        float w = wx * wy;
        dsum += w;
#pragma unroll
        for (int c = 0; c < 36; c++) acc[c] += w * ch[c];
      }
    }
  }
  float inv = 1.f / fmaxf(dsum, 1e-7f);
#pragma unroll
  for (int c = 0; c < 3; c++)
    outImg[((size_t)(b * 6 + dir * 3 + c)) * HW0 + q] = acc[c] * inv;
#pragma unroll
  for (int c = 0; c < 32; c++)
    outFeat[((size_t)(b * 64 + dir * 32 + c)) * HW0 + q] = acc[3 + c] * inv;
  outSig[((size_t)(b * 2 + dir)) * HW0 + q] = acc[35] * inv;
}

template <int C, int Hd, int Wd, int RS, int Z>
__device__ __forceinline__ void gather_feat_body(
    const float* __restrict__ recs, const uint2* __restrict__ cs,
    float* __restrict__ outF, int lb) {
  constexpr int HWd = Hd * Wd;
  constexpr int NCX = Wd + 1;
  constexpr int NC  = (Wd + 1) * (Hd + 1);
  constexpr int GX = HWd / 256;
  constexpr int T = GX * B * 2 * Z;
  lb = (lb & 7) * (T >> 3) + (lb >> 3);
  int q = (lb % GX) * 256 + (int)threadIdx.x;
  int b = (lb / GX) % B;
  int dz = lb / (GX * B);
  int z = dz % Z, dir = dz / Z;
  int c0 = z * 32;
  int nb = dir * B + b;
  int qx = q % Wd, qy = q / Wd;
  float acc[32];
#pragma unroll
  for (int c = 0; c < 32; c++) acc[c] = 0.f;
  float dsum = 0.f;
  for (int ky = 0; ky < 2; ky++) {
    int cy = qy - 1 + ky;
    for (int kx = 0; kx < 2; kx++) {
      int cx = qx - 1 + kx;
      uint2 sc = cs[nb * NC + (cy + 1) * NCX + (cx + 1)];
      unsigned s0 = sc.x, cn = sc.y;
      for (unsigned s = s0; s < s0 + cn; s++) {
        const unsigned* rp = (const unsigned*)(recs + (size_t)s * RS);
        const floatx4* r4 = (const floatx4*)rp;
        floatx4 a0 = r4[4 * z + 0], a1 = r4[4 * z + 1], a2 = r4[4 * z + 2], a3 = r4[4 * z + 3];
        float2 hd = *(const float2*)(rp + C / 2);
        union { floatx4 f; unsigned u[4]; } t;
        float ch[32];
        t.f = a0; h2f(t.u[0], ch[0], ch[1]);  h2f(t.u[1], ch[2], ch[3]);
                  h2f(t.u[2], ch[4], ch[5]);  h2f(t.u[3], ch[6], ch[7]);
        t.f = a1; h2f(t.u[0], ch[8], ch[9]);  h2f(t.u[1], ch[10], ch[11]);
                  h2f(t.u[2], ch[12], ch[13]);h2f(t.u[3], ch[14], ch[15]);
        t.f = a2; h2f(t.u[0], ch[16], ch[17]);h2f(t.u[1], ch[18], ch[19]);
                  h2f(t.u[2], ch[20], ch[21]);h2f(t.u[3], ch[22], ch[23]);
        t.f = a3; h2f(t.u[0], ch[24], ch[25]);h2f(t.u[1], ch[26], ch[27]);
                  h2f(t.u[2], ch[28], ch[29]);h2f(t.u[3], ch[30], ch[31]);
        float dxf = hd.x, dyf = hd.y;
        float wx = kx ? (1.f - dxf) : dxf;
        float wy = ky ? (1.f - dyf) : dyf;
        float w = wx * wy;
        dsum += w;
#pragma unroll
        for (int c = 0; c < 32; c++) acc[c] += w * ch[c];
      }
    }
  }
  float inv = 1.f / fmaxf(dsum, 1e-7f);
  size_t obase = ((size_t)(b * 2 * C + dir * C + c0)) * HWd + q;
#pragma unroll
  for (int c = 0; c < 32; c++) outF[obase + (size_t)c * HWd] = acc[c] * inv;
}

// ================= merged kernels =================

__global__ __launch_bounds__(256) void k_front(
    const float* f01, const float* s01, const float* f10, const float* s10,
    float* flowF, unsigned* cntF,
    const float* img0, const float* img1, float* msum,
    const float* w2, const float* w3, const float* w4, const float* w5, const float* w6,
    _Float16* o2, _Float16* o3, _Float16* o4, _Float16* o5, _Float16* o6) {
  int f = blockIdx.x;
  if (f < NB_IF) d_interflow2(f01, s01, f10, s10, flowF, cntF, f);
  else if (f < NB_IF + NB_MEAN) d_mean(img0, img1, msum, f - NB_IF);
  else d_wtrans(w2, w3, w4, w5, w6, o2, o3, o4, o5, o6, f - NB_IF - NB_MEAN);
}

__global__ __launch_bounds__(256) void k_down_conv1(
    const float* flowF, float* flowH, unsigned* cntH, float* flowQ, unsigned* cntQ,
    const float* img0, const float* img1, const float* msum, float invCnt,
    const float* w1, const float* b1, const float* a1, _Float16* Ah) {
  int f = blockIdx.x;
  if (f < NB_DH) d_downflow2<2, H1, W1>(flowF, flowH, cntH, f);
  else if (f < NB_DH + NB_DQ) d_downflow2<4, H2, W2>(flowF, flowQ, cntQ, f - NB_DH);
  else d_conv1(img0, img1, msum, invCnt, w1, b1, a1, Ah, f - NB_DH - NB_DQ);
}

__global__ __launch_bounds__(256) void k_scan_conv2(
    const unsigned* cntAll, unsigned* tpre, unsigned* psum,
    const _Float16* Ah, const _Float16* wt2, const float* b2, const float* a2,
    _Float16* Bh) {
  int f = blockIdx.x;
  if (f < NCHUNKS) d_scan_part(cntAll, tpre, psum, f);
  else conv_mfma_body<32, 32, 1, 8>(Ah, wt2, b2, a2, Bh, H0, W0, H0, W0,
                                    224, 1, 8, f - NCHUNKS);
}

__global__ __launch_bounds__(256) void k_scan_apply(
    const unsigned* __restrict__ cnt, const unsigned* __restrict__ tpre,
    const unsigned* __restrict__ psum,
    uint2* __restrict__ cs, unsigned* __restrict__ curs) {
  int b = blockIdx.x, t = threadIdx.x;
  int off, sz, ci;
  chunk_map(b, off, sz, ci);
  __shared__ unsigned cbs;
  if (t == 0) {
    int first = (off == 0) ? 0 : (off == SZ_F ? NCH_F : NCH_F + NCH_H);
    unsigned c = 0;
    for (int k = first; k < first + ci; k++) c += psum[k];
    cbs = c;
  }
  __syncthreads();
  int base = off + ci * CHUNK + t * 64;
  int lim = off + min(sz, (ci + 1) * CHUNK);
  unsigned run = cbs + tpre[b * 256 + t];
  for (int j = 0; j < 64; j++) {
    int idx = base + j;
    if (idx < lim) {
      unsigned c = cnt[idx];
      cs[idx] = make_uint2(run, c);
      curs[idx] = run;
      run += c;
    }
  }
}

__global__ __launch_bounds__(256) void k_packF_conv3(
    const float* img0, const float* img1, const float* msum, float invCnt,
    const _Float16* Bh, const float* s01, const float* s10, const float* flowF,
    float* recs, unsigned* cursF,
    const _Float16* wt3, const float* b3, const float* a3, _Float16* Ah) {
  int f = blockIdx.x;
  if (f < NB_PF)
    pack_full_body(img0, img1, msum, invCnt, Bh, s01, s10, flowF, recs, cursF, f);
  else
    conv_mfma_body<32, 64, 2, 4>(Bh, wt3, b3, a3, Ah, H0, W0, H1, W1,
                                 112, 2, 8, f - NB_PF);
}

__global__ __launch_bounds__(256) void k_gatherF_conv4(
    const float* recs, const uint2* csF,
    float* outImg, float* outFeat, float* outSig,
    const _Float16* Ah, const _Float16* wt4, const float* b4, const float* a4,
    _Float16* Bh) {
  int f = blockIdx.x;
  if (f < NB_GF)
    gather_full_body(recs, csF, outImg, outFeat, outSig, f);
  else
    conv_mfma_body<64, 64, 1, 8>(Ah, wt4, b4, a4, Bh, H1, W1, H1, W1,
                                 56, 2, 8, f - NB_GF);
}

__global__ __launch_bounds__(256) void k_packH_conv5(
    const _Float16* Bh, const float* flowH, float* recs, unsigned* cursH,
    const _Float16* wt5, const float* b5, const float* a5, _Float16* Ah) {
  int f = blockIdx.x;
  if (f < NB_PH)
    pack_feat_body<64, H1, W1, RS_H>(Bh, flowH, recs, cursH, f);
  else
    conv_mfma_body<64, 96, 2, 4>(Bh, wt5, b5, a5, Ah, H1, W1, H2, W2,
                                 28, 3, 8, f - NB_PH);
}

__global__ __launch_bounds__(256) void k_gatherH_conv6(
    const float* recs, const uint2* csH, float* outF2,
    const _Float16* Ah, const _Float16* wt6, const float* b6, const float* a6,
    _Float16* Bh) {
  int f = blockIdx.x;
  if (f < NB_GH)
    gather_feat_body<64, H1, W1, RS_H, 2>(recs, csH, outF2, f);
  else
    conv_mfma_body<96, 96, 1, 4>(Ah, wt6, b6, a6, Bh, H2, W2, H2, W2,
                                 28, 3, 8, f - NB_GH);
}

__global__ __launch_bounds__(256) void k_packQ(
    const _Float16* Bh, const float* flowQ, float* recs, unsigned* cursQ) {
  pack_feat_body<96, H2, W2, RS_Q>(Bh, flowQ, recs, cursQ, blockIdx.x);
}

__global__ __launch_bounds__(256) void k_gatherQ(
    const float* recs, const uint2* csQ, float* outF3) {
  gather_feat_body<96, H2, W2, RS_Q, 3>(recs, csQ, outF3, blockIdx.x);
}

extern "C" void kernel_launch(void* const* d_in, const int* in_sizes, int n_in,
                              void* d_out, int out_size, void* d_ws, size_t ws_size,
                              hipStream_t stream) {
  (void)in_sizes; (void)n_in; (void)out_size;
  if (ws_size < WS_FLOATS * sizeof(float)) return;

  const float* img0    = (const float*)d_in[0];
  const float* img1    = (const float*)d_in[1];
  const float* flow01  = (const float*)d_in[2];
  const float* sigma01 = (const float*)d_in[3];
  const float* flow10  = (const float*)d_in[4];
  const float* sigma10 = (const float*)d_in[5];
  const float* wp[6]; const float* bp[6]; const float* ap[6];
  for (int i = 0; i < 6; i++) {
    wp[i] = (const float*)(d_in[6 + 3 * i]);
    bp[i] = (const float*)(d_in[7 + 3 * i]);
    ap[i] = (const float*)(d_in[8 + 3 * i]);
  }
  float* ws  = (float*)d_ws;
  float* out = (float*)d_out;

  unsigned* cntAll  = (unsigned*)(ws + OFF_CNT);
  unsigned* cntF = cntAll;
  unsigned* cntH = cntAll + SZ_F;
  unsigned* cntQ = cntAll + SZ_F + SZ_H;
  uint2*    csAll = (uint2*)(ws + OFF_CS);
  uint2*    csF = csAll, *csH = csAll + SZ_F, *csQ = csAll + SZ_F + SZ_H;
  unsigned* cursAll  = (unsigned*)(ws + OFF_CURS);
  unsigned* cursF = cursAll, *cursH = cursAll + SZ_F, *cursQ = cursAll + SZ_F + SZ_H;
  unsigned* tpre  = (unsigned*)(ws + OFF_TPRE);
  unsigned* psum  = (unsigned*)(ws + OFF_PSUM);
  float*    recs  = ws + OFF_RECS;
  _Float16* Ah = (_Float16*)(ws + OFF_BUFA);
  _Float16* Bh = (_Float16*)(ws + OFF_BUFB);
  _Float16* wt[5] = {(_Float16*)(ws + OFF_WT2), (_Float16*)(ws + OFF_WT3),
                     (_Float16*)(ws + OFF_WT4), (_Float16*)(ws + OFF_WT5),
                     (_Float16*)(ws + OFF_WT6)};
  float* flowF = ws + OFF_FLOW;
  float* flowH = ws + OFF_FLH;
  float* flowQ = ws + OFF_FLQ;

  const float invCnt = 1.f / (6.f * (float)HW0);

  hipMemsetAsync(ws, 0, ZERO_FLOATS * sizeof(float), stream);

  dim3 blk(256);

  // 1: interflow || mean || wtrans
  k_front<<<dim3(NB_IF + NB_MEAN + NB_WT), blk, 0, stream>>>(
      flow01, sigma01, flow10, sigma10, flowF, cntF,
      img0, img1, ws + OFF_MEAN,
      wp[1], wp[2], wp[3], wp[4], wp[5], wt[0], wt[1], wt[2], wt[3], wt[4]);

  // 2: downflowH || downflowQ || conv1
  k_down_conv1<<<dim3(NB_DH + NB_DQ + NB_C1), blk, 0, stream>>>(
      flowF, flowH, cntH, flowQ, cntQ,
      img0, img1, ws + OFF_MEAN, invCnt, wp[0], bp[0], ap[0], Ah);

  // 3: scan_part || conv2
  k_scan_conv2<<<dim3(NCHUNKS + NB_C2), blk, 0, stream>>>(
      cntAll, tpre, psum, Ah, wt[0], bp[1], ap[1], Bh);

  // 4: scan_apply
  k_scan_apply<<<dim3(NCHUNKS), blk, 0, stream>>>(cntAll, tpre, psum, csAll, cursAll);

  // 5: pack_full || conv3
  k_packF_conv3<<<dim3(NB_PF + NB_C3), blk, 0, stream>>>(
      img0, img1, ws + OFF_MEAN, invCnt, Bh, sigma01, sigma10, flowF,
      recs, cursF, wt[1], bp[2], ap[2], Ah);

  // 6: gather_full || conv4
  k_gatherF_conv4<<<dim3(NB_GF + NB_C4), blk, 0, stream>>>(
      recs, csF, out + O_IMG, out + O_F1, out + O_SIG,
      Ah, wt[2], bp[3], ap[3], Bh);

  // 7: pack_H || conv5
  k_packH_conv5<<<dim3(NB_PH + NB_C5), blk, 0, stream>>>(
      Bh, flowH, recs, cursH, wt[3], bp[4], ap[4], Ah);

  // 8: gather_H || conv6
  k_gatherH_conv6<<<dim3(NB_GH + NB_C6), blk, 0, stream>>>(
      recs, csH, out + O_F2, Ah, wt[4], bp[5], ap[5], Bh);

  // 9: pack_Q ; 10: gather_Q
  k_packQ<<<dim3((HW2 / 256) * B * 2), blk, 0, stream>>>(Bh, flowQ, recs, cursQ);
  k_gatherQ<<<dim3((HW2 / 256) * B * 6), blk, 0, stream>>>(recs, csQ, out + O_F3);
}

// Round 14
// 571.832 us; speedup vs baseline: 1.1826x; 1.0031x over previous
//
#include <hip/hip_runtime.h>
#include <hip/hip_fp16.h>

static constexpr int B  = 4;
static constexpr int H0 = 256, W0 = 448, HW0 = H0 * W0;   // full
static constexpr int H1 = 128, W1 = 224, HW1 = H1 * W1;   // half
static constexpr int H2 = 64,  W2 = 112, HW2 = H2 * W2;   // quarter

typedef _Float16 half8_t __attribute__((ext_vector_type(8)));
typedef _Float16 half4_t __attribute__((ext_vector_type(4)));
typedef _Float16 half2v  __attribute__((ext_vector_type(2)));
typedef float floatx4 __attribute__((ext_vector_type(4)));

static constexpr int NC_F = (W0 + 1) * (H0 + 1);
static constexpr int NC_H = (W1 + 1) * (H1 + 1);
static constexpr int NC_Q = (W2 + 1) * (H2 + 1);

static constexpr int RS_F = 20;
static constexpr int RS_H = 36;
static constexpr int RS_Q = 52;

static constexpr int SZ_F = 2 * B * NC_F;
static constexpr int SZ_H = 2 * B * NC_H;
static constexpr int SZ_Q = 2 * B * NC_Q;
static constexpr int CNT_TOTAL = SZ_F + SZ_H + SZ_Q;

static constexpr int CHUNK = 16384;
static constexpr int NCH_F = (SZ_F + CHUNK - 1) / CHUNK;
static constexpr int NCH_H = (SZ_H + CHUNK - 1) / CHUNK;
static constexpr int NCH_Q = (SZ_Q + CHUNK - 1) / CHUNK;
static constexpr int NCHUNKS = NCH_F + NCH_H + NCH_Q;     // 76

// ---------------- workspace layout (floats) ----------------
static constexpr size_t OFF_MEAN   = 0;
static constexpr size_t OFF_CNT    = 256;
static constexpr size_t ZERO_FLOATS = OFF_CNT + CNT_TOTAL;
static constexpr size_t OFF_BUFA   = ZERO_FLOATS;
static constexpr size_t OFF_BUFB   = OFF_BUFA + (size_t)4 * 32 * HW0;
static constexpr size_t OFF_FLOW   = OFF_BUFB + (size_t)4 * 32 * HW0;
static constexpr size_t OFF_FLH    = OFF_FLOW + (size_t)2 * B * 2 * HW0;
static constexpr size_t OFF_FLQ    = OFF_FLH + (size_t)2 * B * 2 * HW1;
static constexpr size_t OFF_WT2 = OFF_FLQ + (size_t)2 * B * 2 * HW2;
static constexpr size_t OFF_WT3 = OFF_WT2 + 4608;
static constexpr size_t OFF_WT4 = OFF_WT3 + 9216;
static constexpr size_t OFF_WT5 = OFF_WT4 + 18432;
static constexpr size_t OFF_WT6 = OFF_WT5 + 27648;
static constexpr size_t OFF_CS   = OFF_WT6 + 41472;
static constexpr size_t OFF_CURS = OFF_CS + (size_t)2 * CNT_TOTAL;
static constexpr size_t OFF_TPRE = OFF_CURS + CNT_TOTAL;
static constexpr size_t OFF_PSUM = OFF_TPRE + (size_t)NCHUNKS * 256;
static constexpr size_t OFF_RECS = OFF_PSUM + 128;
static constexpr size_t WS_FLOATS = OFF_RECS + (size_t)2 * B * HW0 * RS_F;

// ---------------- output layout (floats) ----------------
static constexpr size_t O_IMG = 0;
static constexpr size_t O_F1  = O_IMG + (size_t)B * 6 * HW0;
static constexpr size_t O_F2  = O_F1  + (size_t)B * 64 * HW0;
static constexpr size_t O_F3  = O_F2  + (size_t)B * 128 * HW1;
static constexpr size_t O_SIG = O_F3  + (size_t)B * 192 * HW2;

// sub-grid block counts (all multiples of 8 -> bijective XCD swizzle)
static constexpr int NB_IF = 2 * B * HW0 / 256;   // 3584
static constexpr int NB_MEAN = 32 * B;            // 128
static constexpr int NB_WT = (202752 + 255) / 256;// 792
static constexpr int NB_DH = 2 * B * HW1 / 256;   // 896
static constexpr int NB_DQ = 2 * B * HW2 / 256;   // 224
static constexpr int NB_C1 = 448 * 8;             // 3584
static constexpr int NB_C2 = 224 * 8;             // 1792
static constexpr int NB_PF = (HW0 / 256) * B * 2; // 3584
static constexpr int NB_C3 = 112 * 2 * 8;         // 1792
static constexpr int NB_GF = NB_PF;               // 3584
static constexpr int NB_C4 = 56 * 2 * 8;          // 896
static constexpr int NB_PH = (HW1 / 256) * B * 2; // 896
static constexpr int NB_C5 = 28 * 3 * 8;          // 672
static constexpr int NB_GH = (HW1 / 256) * B * 4; // 1792
static constexpr int NB_C6 = 28 * 3 * 8;          // 672

__device__ inline unsigned f2h(float lo, float hi) {
  __half2 h = __floats2half2_rn(lo, hi);
  return *reinterpret_cast<unsigned*>(&h);
}

__device__ inline void chunk_map(int b, int& off, int& sz, int& ci) {
  if (b < NCH_F)              { off = 0;           sz = SZ_F; ci = b; }
  else if (b < NCH_F + NCH_H) { off = SZ_F;        sz = SZ_H; ci = b - NCH_F; }
  else                        { off = SZ_F + SZ_H; sz = SZ_Q; ci = b - NCH_F - NCH_H; }
}

// ================= device bodies =================

__device__ __forceinline__ void d_mean(const float* __restrict__ img0,
                                       const float* __restrict__ img1,
                                       float* __restrict__ msum, int s) {
  const int perImg = 3 * HW0;
  int bx = s & 31, b = s >> 5;
  float acc = 0.f;
  int tot = 2 * perImg;
  for (int i = bx * 256 + threadIdx.x; i < tot; i += 32 * 256) {
    acc += (i < perImg) ? img0[(size_t)b * perImg + i] : img1[(size_t)b * perImg + (i - perImg)];
  }
#pragma unroll
  for (int o = 32; o > 0; o >>= 1) acc += __shfl_down(acc, o);
  __shared__ float red[4];
  int lane = threadIdx.x & 63, wid = threadIdx.x >> 6;
  if (lane == 0) red[wid] = acc;
  __syncthreads();
  if (threadIdx.x == 0) atomicAdd(&msum[b], red[0] + red[1] + red[2] + red[3]);
}

__device__ __forceinline__ void d_interflow2(
    const float* __restrict__ f01, const float* __restrict__ s01,
    const float* __restrict__ f10, const float* __restrict__ s10,
    float* __restrict__ outBase, unsigned* __restrict__ cntF, int s) {
  constexpr int NCX = W0 + 1;
  int i = s * 256 + (int)threadIdx.x;
  if (i >= 2 * B * HW0) return;
  int nb = i / HW0;
  int px = i - nb * HW0;
  int dir = nb >> 2, b = nb & 3;
  const float* flo = dir ? f10 : f01;
  const float* sigma = dir ? s10 : s01;
  float fx = flo[((size_t)(b * 2 + 0)) * HW0 + px];
  float fy = flo[((size_t)(b * 2 + 1)) * HW0 + px];
  float sg = sigma[(size_t)b * HW0 + px];
  float ftx, fty;
  if (fabsf(sg) < 0.01f) {
    ftx = 0.5f * fx; fty = 0.5f * fy;
  } else {
    float g = (1.f - sqrtf(fmaxf(0.f, 1.f - sg * sg))) / (2.f * sg);
    ftx = 0.5f * fx - g * fy;
    fty = 0.5f * fy + g * fx;
  }
  outBase[((size_t)(nb * 2 + 0)) * HW0 + px] = ftx;
  outBase[((size_t)(nb * 2 + 1)) * HW0 + px] = fty;
  int sw = px % W0, sh = px / W0;
  float tx = (float)sw + ftx, ty = (float)sh + fty;
  int x0 = (int)floorf(tx), y0 = (int)floorf(ty);
  if (x0 >= -1 && x0 <= W0 - 1 && y0 >= -1 && y0 <= H0 - 1)
    atomicAdd(&cntF[nb * NC_F + (y0 + 1) * NCX + (x0 + 1)], 1u);
}

template <int F, int Hd, int Wd>
__device__ __forceinline__ void d_downflow2(
    const float* __restrict__ in, float* __restrict__ out,
    unsigned* __restrict__ cnt, int s) {
  constexpr int HWd = Hd * Wd;
  constexpr int NCX = Wd + 1;
  constexpr int NC  = (Wd + 1) * (Hd + 1);
  int i = s * 256 + (int)threadIdx.x;
  if (i >= 2 * B * HWd) return;
  int nb = i / HWd;
  int px = i - nb * HWd;
  int ow = px % Wd, oh = px / Wd;
  float cy = (oh + 0.5f) * F - 0.5f;
  float cx = (ow + 0.5f) * F - 0.5f;
  int ylo = (int)floorf(cy) - F + 1;
  int xlo = (int)floorf(cx) - F + 1;
  const float* ipx = in + ((size_t)(nb * 2 + 0)) * HW0;
  const float* ipy = in + ((size_t)(nb * 2 + 1)) * HW0;
  float ax = 0.f, ay = 0.f, wn = 0.f;
  for (int jy = 0; jy < 2 * F; jy++) {
    int y = ylo + jy;
    if ((unsigned)y >= (unsigned)H0) continue;
    float wy = 1.f - fabsf((float)y - cy) / (float)F;
    for (int jx = 0; jx < 2 * F; jx++) {
      int x = xlo + jx;
      if ((unsigned)x >= (unsigned)W0) continue;
      float wx = 1.f - fabsf((float)x - cx) / (float)F;
      float ww = wy * wx;
      ax += ww * ipx[(size_t)y * W0 + x];
      ay += ww * ipy[(size_t)y * W0 + x];
      wn += ww;
    }
  }
  float sc = 1.f / (wn * (float)F);
  float fx = ax * sc, fy = ay * sc;
  out[((size_t)(nb * 2 + 0)) * HWd + px] = fx;
  out[((size_t)(nb * 2 + 1)) * HWd + px] = fy;
  float tx = (float)ow + fx, ty = (float)oh + fy;
  int x0 = (int)floorf(tx), y0 = (int)floorf(ty);
  if (x0 >= -1 && x0 <= Wd - 1 && y0 >= -1 && y0 <= Hd - 1)
    atomicAdd(&cnt[nb * NC + (y0 + 1) * NCX + (x0 + 1)], 1u);
}

__device__ __forceinline__ void d_wtrans(
    const float* __restrict__ w2, const float* __restrict__ w3,
    const float* __restrict__ w4, const float* __restrict__ w5,
    const float* __restrict__ w6,
    _Float16* __restrict__ o2, _Float16* __restrict__ o3,
    _Float16* __restrict__ o4, _Float16* __restrict__ o5,
    _Float16* __restrict__ o6, int s) {
  int i = s * 256 + (int)threadIdx.x;
  const float* w; _Float16* o; int COUT, CIN, base;
  if      (i <   9216) { w = w2; o = o2; COUT = 32; CIN = 32; base = 0; }
  else if (i <  27648) { w = w3; o = o3; COUT = 64; CIN = 32; base = 9216; }
  else if (i <  64512) { w = w4; o = o4; COUT = 64; CIN = 64; base = 27648; }
  else if (i < 119808) { w = w5; o = o5; COUT = 96; CIN = 64; base = 64512; }
  else if (i < 202752) { w = w6; o = o6; COUT = 96; CIN = 96; base = 119808; }
  else return;
  int j = i - base;
  int q = j % 9;
  int rest = j / 9;
  int ci = rest % CIN;
  int co = rest / CIN;
  o[((size_t)q * COUT + co) * CIN + ci] = (_Float16)w[j];
}

__device__ __forceinline__ void d_conv1(
    const float* __restrict__ img0, const float* __restrict__ img1,
    const float* __restrict__ msum, float invCnt,
    const float* __restrict__ wgt, const float* __restrict__ bias,
    const float* __restrict__ alpha, _Float16* __restrict__ outp, int s) {
  __shared__ float wsm[32 * 27];
  __shared__ float bsm[32];
  int bx = s % 448, n = s / 448;
  for (int i = threadIdx.x; i < 32 * 27; i += 256) wsm[i] = wgt[i];
  if (threadIdx.x < 32) bsm[threadIdx.x] = bias[threadIdx.x];
  __syncthreads();
  int b = n & 3;
  const float* ip = (n < 4 ? img0 : img1) + (size_t)b * 3 * HW0;
  float m = msum[b] * invCnt;
  int tx = bx % 7, ty = bx / 7;
  int ow = tx * 64 + (threadIdx.x & 63);
  int oh = ty * 4 + (threadIdx.x >> 6);
  float xv[27];
#pragma unroll
  for (int ci = 0; ci < 3; ci++) {
    const float* iq = ip + (size_t)ci * HW0;
#pragma unroll
    for (int ky = 0; ky < 3; ky++) {
      int y = oh - 1 + ky;
      bool yv = (unsigned)y < (unsigned)H0;
      const float* row = iq + (size_t)y * W0;
#pragma unroll
      for (int kx = 0; kx < 3; kx++) {
        int x = ow - 1 + kx;
        xv[ci * 9 + ky * 3 + kx] = (yv && (unsigned)x < (unsigned)W0) ? row[x] - m : 0.f;
      }
    }
  }
  float a = alpha[0];
  _Float16* ob = outp + ((size_t)(n * H0 + oh) * W0 + ow) * 32;
#pragma clang loop unroll(disable)
  for (int g = 0; g < 4; g++) {
    float acc[8];
#pragma unroll
    for (int k = 0; k < 8; k++) acc[k] = bsm[g * 8 + k];
#pragma unroll
    for (int k = 0; k < 8; k++) {
      const float* wp = &wsm[(g * 8 + k) * 27];
#pragma unroll
      for (int j = 0; j < 27; j++) acc[k] += xv[j] * wp[j];
    }
    half8_t h;
#pragma unroll
    for (int k = 0; k < 8; k++) {
      float v = acc[k];
      v = v > 0.f ? v : a * v;
      h[k] = (_Float16)v;
    }
    *(half8_t*)(ob + g * 8) = h;
  }
}

template <int CIN, int COUT, int STRIDE, int TROWS>
__device__ __forceinline__ void conv_mfma_body(
    const _Float16* __restrict__ in, const _Float16* __restrict__ wT,
    const float* __restrict__ bias, const float* __restrict__ alpha,
    _Float16* __restrict__ outp, int Hin, int Win, int Hout, int Wout,
    int gx, int gy, int gz, int lb) {
  int T = gx * gy * gz;
  lb = (lb & 7) * (T >> 3) + (lb >> 3);
  int cob  = lb % gy;
  int n    = (lb / gy) % gz;
  int tile = lb / (gy * gz);
  int lane = threadIdx.x & 63, wave = threadIdx.x >> 6;
  int l15 = lane & 15, lhi = lane >> 4;
  int tiles_x = Wout >> 4;
  int tx = tile % tiles_x, ty = tile / tiles_x;
  int ow0 = tx << 4;
  int oh0 = ty * (4 * TROWS) + wave * TROWS;
  int co0 = cob * 32;
  floatx4 acc[2][TROWS] = {};
  const _Float16* ip = in + (size_t)n * Hin * Win * CIN;
  int x_base = (ow0 + l15) * STRIDE;
  int ybase = oh0 * STRIDE - 1;
  constexpr int NY = (TROWS - 1) * STRIDE + 3;
  const _Float16* wA = wT + (size_t)(co0 + l15) * CIN;
  const _Float16* wB = wT + (size_t)(co0 + 16 + l15) * CIN;
  for (int kc = 0; kc < CIN / 32; kc++) {
    int ci = kc * 32 + lhi * 8;
#pragma unroll
    for (int dxi = 0; dxi < 3; dxi++) {
      int x = x_base + dxi - 1;
      bool xv = (unsigned)x < (unsigned)Win;
      int xc = x < 0 ? 0 : (x >= Win ? Win - 1 : x);
      half8_t a0[3], a1[3];
#pragma unroll
      for (int dy = 0; dy < 3; dy++) {
        int q = dy * 3 + dxi;
        a0[dy] = *(const half8_t*)(wA + (size_t)q * COUT * CIN + ci);
        a1[dy] = *(const half8_t*)(wB + (size_t)q * COUT * CIN + ci);
      }
#pragma unroll
      for (int y6 = 0; y6 < NY; y6++) {
        int y = ybase + y6;
        if ((unsigned)y >= (unsigned)Hin) continue;   // wave-uniform; skip == zero-pad
        half8_t bf = *(const half8_t*)(ip + ((size_t)y * Win + xc) * CIN + ci);
        half8_t z = {};
        bf = xv ? bf : z;
#pragma unroll
        for (int dy = 0; dy < 3; dy++) {
          int tnum = y6 - dy;
          if (tnum < 0 || tnum % STRIDE != 0) continue;
          int t = tnum / STRIDE;
          if (t >= TROWS) continue;
          acc[0][t] = __builtin_amdgcn_mfma_f32_16x16x32_f16(a0[dy], bf, acc[0][t], 0, 0, 0);
          acc[1][t] = __builtin_amdgcn_mfma_f32_16x16x32_f16(a1[dy], bf, acc[1][t], 0, 0, 0);
        }
      }
    }
  }
  float aP = alpha[0];
#pragma unroll
  for (int h = 0; h < 2; h++) {
    float bia[4];
#pragma unroll
    for (int r = 0; r < 4; r++) bia[r] = bias[co0 + h * 16 + lhi * 4 + r];
#pragma unroll
    for (int t = 0; t < TROWS; t++) {
      half4_t hh;
#pragma unroll
      for (int r = 0; r < 4; r++) {
        float v = acc[h][t][r] + bia[r];
        v = v > 0.f ? v : aP * v;
        hh[r] = (_Float16)v;
      }
      *(half4_t*)(outp + (((size_t)n * Hout + oh0 + t) * Wout + ow0 + l15) * COUT +
                  co0 + h * 16 + lhi * 4) = hh;
    }
  }
}

__device__ __forceinline__ void d_scan_part(
    const unsigned* __restrict__ cnt, unsigned* __restrict__ tpre,
    unsigned* __restrict__ psum, int b) {
  int t = threadIdx.x;
  int off, sz, ci;
  chunk_map(b, off, sz, ci);
  int base = off + ci * CHUNK + t * 64;
  int lim = off + min(sz, (ci + 1) * CHUNK);
  unsigned s = 0;
  for (int j = 0; j < 64; j++) {
    int idx = base + j;
    if (idx < lim) s += cnt[idx];
  }
  __shared__ unsigned sm[256];
  sm[t] = s;
  __syncthreads();
  for (int o = 1; o < 256; o <<= 1) {
    unsigned v = (t >= o) ? sm[t - o] : 0u;
    __syncthreads();
    sm[t] += v;
    __syncthreads();
  }
  unsigned incl = sm[t];
  tpre[b * 256 + t] = incl - s;
  if (t == 255) psum[b] = incl;
}

__device__ __forceinline__ void pack_full_body(
    const float* __restrict__ img0, const float* __restrict__ img1,
    const float* __restrict__ msum, float invCnt,
    const _Float16* __restrict__ featN,
    const float* __restrict__ s01, const float* __restrict__ s10,
    const float* __restrict__ flowB,
    float* __restrict__ recs, unsigned* __restrict__ curs, int s) {
  constexpr int NCX = W0 + 1;
  constexpr int GX = HW0 / 256;
  int px = (s % GX) * 256 + (int)threadIdx.x;
  int b = (s / GX) % B;
  int dir = s / (GX * B);
  int nb = dir * B + b;
  float fx = flowB[((size_t)(nb * 2 + 0)) * HW0 + px];
  float fy = flowB[((size_t)(nb * 2 + 1)) * HW0 + px];
  int sw = px % W0, sh = px / W0;
  float tx = (float)sw + fx, ty = (float)sh + fy;
  float x0f = floorf(tx), y0f = floorf(ty);
  int x0 = (int)x0f, y0 = (int)y0f;
  if (x0 < -1 || x0 > W0 - 1 || y0 < -1 || y0 > H0 - 1) return;
  const float* imp = (dir ? img1 : img0) + (size_t)b * 3 * HW0;
  float m = msum[b] * invCnt;
  float im0 = imp[px] - m, im1 = imp[(size_t)HW0 + px] - m, im2 = imp[(size_t)2 * HW0 + px] - m;
  const float* sig = dir ? s10 : s01;
  float sg = sig[(size_t)b * HW0 + px];
  union { floatx4 f4[RS_F / 4]; unsigned u[RS_F]; } r;
  r.u[0] = f2h(im0, im1);
  r.u[1] = f2h(im2, sg);
  const floatx4* fp = (const floatx4*)(featN + ((size_t)nb * HW0 + px) * 32);
  union { floatx4 f; unsigned u[4]; } t;
#pragma unroll
  for (int j = 0; j < 4; j++) {
    t.f = fp[j];
    r.u[2 + 4 * j + 0] = t.u[0]; r.u[2 + 4 * j + 1] = t.u[1];
    r.u[2 + 4 * j + 2] = t.u[2]; r.u[2 + 4 * j + 3] = t.u[3];
  }
  r.u[18] = __float_as_uint(tx - x0f);
  r.u[19] = __float_as_uint(ty - y0f);
  unsigned slot = atomicAdd(&curs[nb * NC_F + (y0 + 1) * NCX + (x0 + 1)], 1u);
  floatx4* o = (floatx4*)(recs + (size_t)slot * RS_F);
#pragma unroll
  for (int j = 0; j < RS_F / 4; j++) o[j] = r.f4[j];
}

template <int C, int Hd, int Wd, int RS>
__device__ __forceinline__ void pack_feat_body(
    const _Float16* __restrict__ featN, const float* __restrict__ flowB,
    float* __restrict__ recs, unsigned* __restrict__ curs, int s) {
  constexpr int HWd = Hd * Wd;
  constexpr int NCX = Wd + 1;
  constexpr int NC  = (Wd + 1) * (Hd + 1);
  constexpr int GX = HWd / 256;
  int px = (s % GX) * 256 + (int)threadIdx.x;
  int b = (s / GX) % B;
  int dir = s / (GX * B);
  int nb = dir * B + b;
  float fx = flowB[((size_t)(nb * 2 + 0)) * HWd + px];
  float fy = flowB[((size_t)(nb * 2 + 1)) * HWd + px];
  int sw = px % Wd, sh = px / Wd;
  float tx = (float)sw + fx, ty = (float)sh + fy;
  float x0f = floorf(tx), y0f = floorf(ty);
  int x0 = (int)x0f, y0 = (int)y0f;
  if (x0 < -1 || x0 > Wd - 1 || y0 < -1 || y0 > Hd - 1) return;
  union { floatx4 f4[RS / 4]; unsigned u[RS]; } r;
  const floatx4* fp = (const floatx4*)(featN + ((size_t)nb * HWd + px) * C);
#pragma unroll
  for (int j = 0; j < C / 8; j++) r.f4[j] = fp[j];
  r.u[C / 2]     = __float_as_uint(tx - x0f);
  r.u[C / 2 + 1] = __float_as_uint(ty - y0f);
#pragma unroll
  for (int j = C / 2 + 2; j < RS; j++) r.u[j] = 0;
  unsigned slot = atomicAdd(&curs[nb * NC + (y0 + 1) * NCX + (x0 + 1)], 1u);
  floatx4* o = (floatx4*)(recs + (size_t)slot * RS);
#pragma unroll
  for (int j = 0; j < RS / 4; j++) o[j] = r.f4[j];
}

// ---- gathers: packed-f16 accumulation (v_pk_fma_f16), f32 weights/denominator ----

__device__ __forceinline__ void gather_full_body(
    const float* __restrict__ recs, const uint2* __restrict__ cs,
    float* __restrict__ outImg, float* __restrict__ outFeat,
    float* __restrict__ outSig, int lb) {
  constexpr int NCX = W0 + 1;
  constexpr int GX = HW0 / 256;
  constexpr int T = GX * B * 2;
  lb = (lb & 7) * (T >> 3) + (lb >> 3);
  int q = (lb % GX) * 256 + (int)threadIdx.x;
  int b = (lb / GX) % B;
  int dir = lb / (GX * B);
  int nb = dir * B + b;
  int qx = q % W0, qy = q / W0;
  half2v ha[18];
#pragma unroll
  for (int j = 0; j < 18; j++) ha[j] = half2v{(_Float16)0.f, (_Float16)0.f};
  float dsum = 0.f;
  for (int ky = 0; ky < 2; ky++) {
    int cy = qy - 1 + ky;
    for (int kx = 0; kx < 2; kx++) {
      int cx = qx - 1 + kx;
      uint2 sc = cs[nb * NC_F + (cy + 1) * NCX + (cx + 1)];
      unsigned s0 = sc.x, cn = sc.y;
      for (unsigned s = s0; s < s0 + cn; s++) {
        const floatx4* r4 = (const floatx4*)(recs + (size_t)s * RS_F);
        union { floatx4 f; half2v h[4]; } t0, t1, t2, t3, t4;
        t0.f = r4[0]; t1.f = r4[1]; t2.f = r4[2]; t3.f = r4[3]; t4.f = r4[4];
        float dxf = t4.f[2], dyf = t4.f[3];
        float wx = kx ? (1.f - dxf) : dxf;
        float wy = ky ? (1.f - dyf) : dyf;
        float w = wx * wy;
        dsum += w;
        _Float16 wh = (_Float16)w;
        half2v ww = {wh, wh};
#pragma unroll
        for (int j = 0; j < 4; j++) ha[j]      += t0.h[j] * ww;
#pragma unroll
        for (int j = 0; j < 4; j++) ha[4 + j]  += t1.h[j] * ww;
#pragma unroll
        for (int j = 0; j < 4; j++) ha[8 + j]  += t2.h[j] * ww;
#pragma unroll
        for (int j = 0; j < 4; j++) ha[12 + j] += t3.h[j] * ww;
        ha[16] += t4.h[0] * ww;
        ha[17] += t4.h[1] * ww;
      }
    }
  }
  float inv = 1.f / fmaxf(dsum, 1e-7f);
  // layout: ha0=(im0,im1) ha1=(im2,sig) ha2..17 = feat c0..31
  outImg[((size_t)(b * 6 + dir * 3 + 0)) * HW0 + q] = (float)ha[0][0] * inv;
  outImg[((size_t)(b * 6 + dir * 3 + 1)) * HW0 + q] = (float)ha[0][1] * inv;
  outImg[((size_t)(b * 6 + dir * 3 + 2)) * HW0 + q] = (float)ha[1][0] * inv;
  outSig[((size_t)(b * 2 + dir)) * HW0 + q]         = (float)ha[1][1] * inv;
#pragma unroll
  for (int j = 0; j < 16; j++) {
    outFeat[((size_t)(b * 64 + dir * 32 + 2 * j + 0)) * HW0 + q] = (float)ha[2 + j][0] * inv;
    outFeat[((size_t)(b * 64 + dir * 32 + 2 * j + 1)) * HW0 + q] = (float)ha[2 + j][1] * inv;
  }
}

template <int C, int Hd, int Wd, int RS, int Z>
__device__ __forceinline__ void gather_feat_body(
    const float* __restrict__ recs, const uint2* __restrict__ cs,
    float* __restrict__ outF, int lb) {
  constexpr int HWd = Hd * Wd;
  constexpr int NCX = Wd + 1;
  constexpr int NC  = (Wd + 1) * (Hd + 1);
  constexpr int GX = HWd / 256;
  constexpr int T = GX * B * 2 * Z;
  lb = (lb & 7) * (T >> 3) + (lb >> 3);
  int q = (lb % GX) * 256 + (int)threadIdx.x;
  int b = (lb / GX) % B;
  int dz = lb / (GX * B);
  int z = dz % Z, dir = dz / Z;
  int c0 = z * 32;
  int nb = dir * B + b;
  int qx = q % Wd, qy = q / Wd;
  half2v ha[16];
#pragma unroll
  for (int j = 0; j < 16; j++) ha[j] = half2v{(_Float16)0.f, (_Float16)0.f};
  float dsum = 0.f;
  for (int ky = 0; ky < 2; ky++) {
    int cy = qy - 1 + ky;
    for (int kx = 0; kx < 2; kx++) {
      int cx = qx - 1 + kx;
      uint2 sc = cs[nb * NC + (cy + 1) * NCX + (cx + 1)];
      unsigned s0 = sc.x, cn = sc.y;
      for (unsigned s = s0; s < s0 + cn; s++) {
        const float* rp = recs + (size_t)s * RS;
        const floatx4* r4 = (const floatx4*)rp;
        union { floatx4 f; half2v h[4]; } t0, t1, t2, t3;
        t0.f = r4[4 * z + 0]; t1.f = r4[4 * z + 1];
        t2.f = r4[4 * z + 2]; t3.f = r4[4 * z + 3];
        float2 hd = *(const float2*)(rp + C / 2);
        float dxf = hd.x, dyf = hd.y;
        float wx = kx ? (1.f - dxf) : dxf;
        float wy = ky ? (1.f - dyf) : dyf;
        float w = wx * wy;
        dsum += w;
        _Float16 wh = (_Float16)w;
        half2v ww = {wh, wh};
#pragma unroll
        for (int j = 0; j < 4; j++) ha[j]      += t0.h[j] * ww;
#pragma unroll
        for (int j = 0; j < 4; j++) ha[4 + j]  += t1.h[j] * ww;
#pragma unroll
        for (int j = 0; j < 4; j++) ha[8 + j]  += t2.h[j] * ww;
#pragma unroll
        for (int j = 0; j < 4; j++) ha[12 + j] += t3.h[j] * ww;
      }
    }
  }
  float inv = 1.f / fmaxf(dsum, 1e-7f);
  size_t obase = ((size_t)(b * 2 * C + dir * C + c0)) * HWd + q;
#pragma unroll
  for (int j = 0; j < 16; j++) {
    outF[obase + (size_t)(2 * j + 0) * HWd] = (float)ha[j][0] * inv;
    outF[obase + (size_t)(2 * j + 1) * HWd] = (float)ha[j][1] * inv;
  }
}

// ================= merged kernels =================

__global__ __launch_bounds__(256) void k_front(
    const float* f01, const float* s01, const float* f10, const float* s10,
    float* flowF, unsigned* cntF,
    const float* img0, const float* img1, float* msum,
    const float* w2, const float* w3, const float* w4, const float* w5, const float* w6,
    _Float16* o2, _Float16* o3, _Float16* o4, _Float16* o5, _Float16* o6) {
  int f = blockIdx.x;
  if (f < NB_IF) d_interflow2(f01, s01, f10, s10, flowF, cntF, f);
  else if (f < NB_IF + NB_MEAN) d_mean(img0, img1, msum, f - NB_IF);
  else d_wtrans(w2, w3, w4, w5, w6, o2, o3, o4, o5, o6, f - NB_IF - NB_MEAN);
}

__global__ __launch_bounds__(256) void k_down_conv1(
    const float* flowF, float* flowH, unsigned* cntH, float* flowQ, unsigned* cntQ,
    const float* img0, const float* img1, const float* msum, float invCnt,
    const float* w1, const float* b1, const float* a1, _Float16* Ah) {
  int f = blockIdx.x;
  if (f < NB_DH) d_downflow2<2, H1, W1>(flowF, flowH, cntH, f);
  else if (f < NB_DH + NB_DQ) d_downflow2<4, H2, W2>(flowF, flowQ, cntQ, f - NB_DH);
  else d_conv1(img0, img1, msum, invCnt, w1, b1, a1, Ah, f - NB_DH - NB_DQ);
}

__global__ __launch_bounds__(256) void k_scan_conv2(
    const unsigned* cntAll, unsigned* tpre, unsigned* psum,
    const _Float16* Ah, const _Float16* wt2, const float* b2, const float* a2,
    _Float16* Bh) {
  int f = blockIdx.x;
  if (f < NCHUNKS) d_scan_part(cntAll, tpre, psum, f);
  else conv_mfma_body<32, 32, 1, 8>(Ah, wt2, b2, a2, Bh, H0, W0, H0, W0,
                                    224, 1, 8, f - NCHUNKS);
}

__global__ __launch_bounds__(256) void k_scan_apply(
    const unsigned* __restrict__ cnt, const unsigned* __restrict__ tpre,
    const unsigned* __restrict__ psum,
    uint2* __restrict__ cs, unsigned* __restrict__ curs) {
  int b = blockIdx.x, t = threadIdx.x;
  int off, sz, ci;
  chunk_map(b, off, sz, ci);
  __shared__ unsigned cbs;
  if (t == 0) {
    int first = (off == 0) ? 0 : (off == SZ_F ? NCH_F : NCH_F + NCH_H);
    unsigned c = 0;
    for (int k = first; k < first + ci; k++) c += psum[k];
    cbs = c;
  }
  __syncthreads();
  int base = off + ci * CHUNK + t * 64;
  int lim = off + min(sz, (ci + 1) * CHUNK);
  unsigned run = cbs + tpre[b * 256 + t];
  for (int j = 0; j < 64; j++) {
    int idx = base + j;
    if (idx < lim) {
      unsigned c = cnt[idx];
      cs[idx] = make_uint2(run, c);
      curs[idx] = run;
      run += c;
    }
  }
}

__global__ __launch_bounds__(256) void k_packF_conv3(
    const float* img0, const float* img1, const float* msum, float invCnt,
    const _Float16* Bh, const float* s01, const float* s10, const float* flowF,
    float* recs, unsigned* cursF,
    const _Float16* wt3, const float* b3, const float* a3, _Float16* Ah) {
  int f = blockIdx.x;
  if (f < NB_PF)
    pack_full_body(img0, img1, msum, invCnt, Bh, s01, s10, flowF, recs, cursF, f);
  else
    conv_mfma_body<32, 64, 2, 4>(Bh, wt3, b3, a3, Ah, H0, W0, H1, W1,
                                 112, 2, 8, f - NB_PF);
}

__global__ __launch_bounds__(256) void k_gatherF_conv4(
    const float* recs, const uint2* csF,
    float* outImg, float* outFeat, float* outSig,
    const _Float16* Ah, const _Float16* wt4, const float* b4, const float* a4,
    _Float16* Bh) {
  int f = blockIdx.x;
  if (f < NB_GF)
    gather_full_body(recs, csF, outImg, outFeat, outSig, f);
  else
    conv_mfma_body<64, 64, 1, 8>(Ah, wt4, b4, a4, Bh, H1, W1, H1, W1,
                                 56, 2, 8, f - NB_GF);
}

__global__ __launch_bounds__(256) void k_packH_conv5(
    const _Float16* Bh, const float* flowH, float* recs, unsigned* cursH,
    const _Float16* wt5, const float* b5, const float* a5, _Float16* Ah) {
  int f = blockIdx.x;
  if (f < NB_PH)
    pack_feat_body<64, H1, W1, RS_H>(Bh, flowH, recs, cursH, f);
  else
    conv_mfma_body<64, 96, 2, 4>(Bh, wt5, b5, a5, Ah, H1, W1, H2, W2,
                                 28, 3, 8, f - NB_PH);
}

__global__ __launch_bounds__(256) void k_gatherH_conv6(
    const float* recs, const uint2* csH, float* outF2,
    const _Float16* Ah, const _Float16* wt6, const float* b6, const float* a6,
    _Float16* Bh) {
  int f = blockIdx.x;
  if (f < NB_GH)
    gather_feat_body<64, H1, W1, RS_H, 2>(recs, csH, outF2, f);
  else
    conv_mfma_body<96, 96, 1, 4>(Ah, wt6, b6, a6, Bh, H2, W2, H2, W2,
                                 28, 3, 8, f - NB_GH);
}

__global__ __launch_bounds__(256) void k_packQ(
    const _Float16* Bh, const float* flowQ, float* recs, unsigned* cursQ) {
  pack_feat_body<96, H2, W2, RS_Q>(Bh, flowQ, recs, cursQ, blockIdx.x);
}

__global__ __launch_bounds__(256) void k_gatherQ(
    const float* recs, const uint2* csQ, float* outF3) {
  gather_feat_body<96, H2, W2, RS_Q, 3>(recs, csQ, outF3, blockIdx.x);
}

extern "C" void kernel_launch(void* const* d_in, const int* in_sizes, int n_in,
                              void* d_out, int out_size, void* d_ws, size_t ws_size,
                              hipStream_t stream) {
  (void)in_sizes; (void)n_in; (void)out_size;
  if (ws_size < WS_FLOATS * sizeof(float)) return;

  const float* img0    = (const float*)d_in[0];
  const float* img1    = (const float*)d_in[1];
  const float* flow01  = (const float*)d_in[2];
  const float* sigma01 = (const float*)d_in[3];
  const float* flow10  = (const float*)d_in[4];
  const float* sigma10 = (const float*)d_in[5];
  const float* wp[6]; const float* bp[6]; const float* ap[6];
  for (int i = 0; i < 6; i++) {
    wp[i] = (const float*)(d_in[6 + 3 * i]);
    bp[i] = (const float*)(d_in[7 + 3 * i]);
    ap[i] = (const float*)(d_in[8 + 3 * i]);
  }
  float* ws  = (float*)d_ws;
  float* out = (float*)d_out;

  unsigned* cntAll  = (unsigned*)(ws + OFF_CNT);
  unsigned* cntF = cntAll;
  unsigned* cntH = cntAll + SZ_F;
  unsigned* cntQ = cntAll + SZ_F + SZ_H;
  uint2*    csAll = (uint2*)(ws + OFF_CS);
  uint2*    csF = csAll, *csH = csAll + SZ_F, *csQ = csAll + SZ_F + SZ_H;
  unsigned* cursAll  = (unsigned*)(ws + OFF_CURS);
  unsigned* cursF = cursAll, *cursH = cursAll + SZ_F, *cursQ = cursAll + SZ_F + SZ_H;
  unsigned* tpre  = (unsigned*)(ws + OFF_TPRE);
  unsigned* psum  = (unsigned*)(ws + OFF_PSUM);
  float*    recs  = ws + OFF_RECS;
  _Float16* Ah = (_Float16*)(ws + OFF_BUFA);
  _Float16* Bh = (_Float16*)(ws + OFF_BUFB);
  _Float16* wt[5] = {(_Float16*)(ws + OFF_WT2), (_Float16*)(ws + OFF_WT3),
                     (_Float16*)(ws + OFF_WT4), (_Float16*)(ws + OFF_WT5),
                     (_Float16*)(ws + OFF_WT6)};
  float* flowF = ws + OFF_FLOW;
  float* flowH = ws + OFF_FLH;
  float* flowQ = ws + OFF_FLQ;

  const float invCnt = 1.f / (6.f * (float)HW0);

  hipMemsetAsync(ws, 0, ZERO_FLOATS * sizeof(float), stream);

  dim3 blk(256);

  // 1: interflow || mean || wtrans
  k_front<<<dim3(NB_IF + NB_MEAN + NB_WT), blk, 0, stream>>>(
      flow01, sigma01, flow10, sigma10, flowF, cntF,
      img0, img1, ws + OFF_MEAN,
      wp[1], wp[2], wp[3], wp[4], wp[5], wt[0], wt[1], wt[2], wt[3], wt[4]);

  // 2: downflowH || downflowQ || conv1
  k_down_conv1<<<dim3(NB_DH + NB_DQ + NB_C1), blk, 0, stream>>>(
      flowF, flowH, cntH, flowQ, cntQ,
      img0, img1, ws + OFF_MEAN, invCnt, wp[0], bp[0], ap[0], Ah);

  // 3: scan_part || conv2
  k_scan_conv2<<<dim3(NCHUNKS + NB_C2), blk, 0, stream>>>(
      cntAll, tpre, psum, Ah, wt[0], bp[1], ap[1], Bh);

  // 4: scan_apply
  k_scan_apply<<<dim3(NCHUNKS), blk, 0, stream>>>(cntAll, tpre, psum, csAll, cursAll);

  // 5: pack_full || conv3
  k_packF_conv3<<<dim3(NB_PF + NB_C3), blk, 0, stream>>>(
      img0, img1, ws + OFF_MEAN, invCnt, Bh, sigma01, sigma10, flowF,
      recs, cursF, wt[1], bp[2], ap[2], Ah);

  // 6: gather_full || conv4
  k_gatherF_conv4<<<dim3(NB_GF + NB_C4), blk, 0, stream>>>(
      recs, csF, out + O_IMG, out + O_F1, out + O_SIG,
      Ah, wt[2], bp[3], ap[3], Bh);

  // 7: pack_H || conv5
  k_packH_conv5<<<dim3(NB_PH + NB_C5), blk, 0, stream>>>(
      Bh, flowH, recs, cursH, wt[3], bp[4], ap[4], Ah);

  // 8: gather_H || conv6
  k_gatherH_conv6<<<dim3(NB_GH + NB_C6), blk, 0, stream>>>(
      recs, csH, out + O_F2, Ah, wt[4], bp[5], ap[5], Bh);

  // 9: pack_Q ; 10: gather_Q
  k_packQ<<<dim3((HW2 / 256) * B * 2), blk, 0, stream>>>(Bh, flowQ, recs, cursQ);
  k_gatherQ<<<dim3((HW2 / 256) * B * 6), blk, 0, stream>>>(recs, csQ, out + O_F3);
}